// Round 1
// baseline (1727.105 us; speedup 1.0000x reference)
//
#include <hip/hip_runtime.h>
#include <math.h>

// SALAD head, fp32 correctness-first implementation.
// B=64, C=1536, N=256 (16x16), HID=512, L=128, M=64, G=256. BNT = B*N = 16384.
#define BNT 16384

// ---------------- token MLP: tok = relu(t@Wt1^T+bt1)@Wt2^T+bt2 ----------------
__global__ __launch_bounds__(256) void token_kernel(
    const float* __restrict__ t, const float* __restrict__ Wt1,
    const float* __restrict__ bt1, const float* __restrict__ Wt2,
    const float* __restrict__ bt2, float* __restrict__ TK) {
  const int b = blockIdx.x, tid = threadIdx.x;
  const int lane = tid & 63, wave = tid >> 6;
  __shared__ float tb[1536];
  __shared__ float h[512];
  for (int i = tid; i < 1536; i += 256) tb[i] = t[b * 1536 + i];
  __syncthreads();
  for (int u = wave; u < 512; u += 4) {
    const float* wr = &Wt1[u * 1536];
    float a = 0.f;
    for (int c = lane; c < 1536; c += 64) a += wr[c] * tb[c];
#pragma unroll
    for (int off = 32; off; off >>= 1) a += __shfl_down(a, off);
    if (lane == 0) h[u] = fmaxf(a + bt1[u], 0.f);
  }
  __syncthreads();
  for (int g = wave; g < 256; g += 4) {
    const float* wr = &Wt2[g * 512];
    float a = 0.f;
    for (int c = lane; c < 512; c += 64) a += wr[c] * h[c];
#pragma unroll
    for (int off = 32; off; off >>= 1) a += __shfl_down(a, off);
    if (lane == 0) TK[b * 256 + g] = a + bt2[g];
  }
}

// ---------------- tiled GEMM: C[M][BNT] = (relu?)(A[M][K] @ B[K][BNT] + bias) ----
// XVIEW: B element (c, j=b*256+n) lives at x[b*393216 + c*256 + n].
template <bool XVIEW, bool RELU>
__global__ __launch_bounds__(256) void gemm_tile(
    const float* __restrict__ A, const float* __restrict__ Bsrc,
    const float* __restrict__ bias, float* __restrict__ Cout, int K) {
  __shared__ float As[16][68];   // As[k][m]  (A tile transposed)
  __shared__ float Bsh[16][68];  // Bsh[k][n]
  const int tid = threadIdx.x;
  const int tx = tid & 15, ty = tid >> 4;
  const int rowBase = blockIdx.y * 64;
  const int colBase = blockIdx.x * 64;
  const int bb = colBase >> 8, n0 = colBase & 255;
  const int boff = XVIEW ? (bb * 393216 + n0) : colBase;
  const int la_row = tid >> 2, la_kq = (tid & 3) << 2;  // A loader: row, k-quad
  const int lb_k = tid >> 4, lb_c = (tid & 15) << 2;    // B loader: k, col-quad

  float acc[4][4];
#pragma unroll
  for (int r = 0; r < 4; ++r)
#pragma unroll
    for (int c = 0; c < 4; ++c) acc[r][c] = 0.f;

  for (int k0 = 0; k0 < K; k0 += 16) {
    const float4 av = *(const float4*)&A[(rowBase + la_row) * K + k0 + la_kq];
    float4 bv;
    if (XVIEW)
      bv = *(const float4*)&Bsrc[boff + (k0 + lb_k) * 256 + lb_c];
    else
      bv = *(const float4*)&Bsrc[(k0 + lb_k) * BNT + boff + lb_c];
    As[la_kq + 0][la_row] = av.x;
    As[la_kq + 1][la_row] = av.y;
    As[la_kq + 2][la_row] = av.z;
    As[la_kq + 3][la_row] = av.w;
    *(float4*)&Bsh[lb_k][lb_c] = bv;
    __syncthreads();
#pragma unroll
    for (int kk = 0; kk < 16; ++kk) {
      const float4 a4 = *(const float4*)&As[kk][ty << 2];
      const float4 b4 = *(const float4*)&Bsh[kk][tx << 2];
      acc[0][0] = fmaf(a4.x, b4.x, acc[0][0]);
      acc[0][1] = fmaf(a4.x, b4.y, acc[0][1]);
      acc[0][2] = fmaf(a4.x, b4.z, acc[0][2]);
      acc[0][3] = fmaf(a4.x, b4.w, acc[0][3]);
      acc[1][0] = fmaf(a4.y, b4.x, acc[1][0]);
      acc[1][1] = fmaf(a4.y, b4.y, acc[1][1]);
      acc[1][2] = fmaf(a4.y, b4.z, acc[1][2]);
      acc[1][3] = fmaf(a4.y, b4.w, acc[1][3]);
      acc[2][0] = fmaf(a4.z, b4.x, acc[2][0]);
      acc[2][1] = fmaf(a4.z, b4.y, acc[2][1]);
      acc[2][2] = fmaf(a4.z, b4.z, acc[2][2]);
      acc[2][3] = fmaf(a4.z, b4.w, acc[2][3]);
      acc[3][0] = fmaf(a4.w, b4.x, acc[3][0]);
      acc[3][1] = fmaf(a4.w, b4.y, acc[3][1]);
      acc[3][2] = fmaf(a4.w, b4.z, acc[3][2]);
      acc[3][3] = fmaf(a4.w, b4.w, acc[3][3]);
    }
    __syncthreads();
  }
#pragma unroll
  for (int r = 0; r < 4; ++r) {
    const int row = rowBase + (ty << 2) + r;
    const float bsv = bias[row];
    float4 o;
    o.x = acc[r][0] + bsv;
    o.y = acc[r][1] + bsv;
    o.z = acc[r][2] + bsv;
    o.w = acc[r][3] + bsv;
    if (RELU) {
      o.x = fmaxf(o.x, 0.f);
      o.y = fmaxf(o.y, 0.f);
      o.z = fmaxf(o.z, 0.f);
      o.w = fmaxf(o.w, 0.f);
    }
    *(float4*)&Cout[row * BNT + colBase + (tx << 2)] = o;
  }
}

// ---------------- Sinkhorn (log domain, 3 iters, dustbin row) ----------------
__global__ __launch_bounds__(256) void sinkhorn_kernel(
    const float* __restrict__ S, const float* __restrict__ dustp,
    float* __restrict__ P) {
  const int b = blockIdx.x, tid = threadIdx.x;
  const int lane = tid & 63, wave = tid >> 6;
  __shared__ float Ms[65][256];
  __shared__ float u[65];
  __shared__ float v[256];
  const float dust = dustp[0];
  for (int idx = tid; idx < 16384; idx += 256) {
    const int m = idx >> 8, n = idx & 255;
    Ms[m][n] = S[m * BNT + b * 256 + n];
  }
  Ms[64][tid] = dust;
  v[tid] = 0.f;
  if (tid < 65) u[tid] = 0.f;
  const float norm = -logf(320.f);        // -log(n+m)
  const float la_dust = norm + logf(192.f);  // dustbin row mass
  __syncthreads();
  for (int it = 0; it < 3; ++it) {
    // u = log_a - lse_n(Ms + v)
    for (int i = wave; i < 65; i += 4) {
      const float x0 = Ms[i][lane] + v[lane];
      const float x1 = Ms[i][lane + 64] + v[lane + 64];
      const float x2 = Ms[i][lane + 128] + v[lane + 128];
      const float x3 = Ms[i][lane + 192] + v[lane + 192];
      float mm = fmaxf(fmaxf(x0, x1), fmaxf(x2, x3));
#pragma unroll
      for (int off = 32; off; off >>= 1) mm = fmaxf(mm, __shfl_xor(mm, off));
      float s = expf(x0 - mm) + expf(x1 - mm) + expf(x2 - mm) + expf(x3 - mm);
#pragma unroll
      for (int off = 32; off; off >>= 1) s += __shfl_xor(s, off);
      if (lane == 0) u[i] = (i == 64 ? la_dust : norm) - (logf(s) + mm);
    }
    __syncthreads();
    // v = log_b - lse_i(Ms + u); one column per thread
    {
      const int n = tid;
      float mm = -1e30f;
      for (int i = 0; i < 65; ++i) mm = fmaxf(mm, Ms[i][n] + u[i]);
      float s = 0.f;
      for (int i = 0; i < 65; ++i) s += expf(Ms[i][n] + u[i] - mm);
      v[n] = norm - (logf(s) + mm);
    }
    __syncthreads();
  }
  for (int idx = tid; idx < 16384; idx += 256) {
    const int m = idx >> 8, n = idx & 255;
    P[b * 16384 + idx] = expf(Ms[m][n] + u[m] + v[n] - norm);
  }
}

// ---------------- VLAD: V[b][l][m] = sum_n f[l][b*256+n] * p[b][m][n] --------
// P tile in LDS with 16B-quad XOR swizzle to avoid same-bank column reads.
__device__ __forceinline__ int ps_idx(int m, int n) {
  return m * 256 + ((((n >> 2) ^ (m & 7)) << 2) | (n & 3));
}
__global__ __launch_bounds__(256) void vlad_kernel(const float* __restrict__ F,
                                                   const float* __restrict__ P,
                                                   float* __restrict__ VL) {
  const int b = blockIdx.x, half = blockIdx.y;
  const int tid = threadIdx.x;
  const int m = tid & 63, lg = tid >> 6;
  __shared__ float ps[64 * 256];
  for (int idx = tid; idx < 16384; idx += 256) {
    const int mm = idx >> 8, n = idx & 255;
    ps[ps_idx(mm, n)] = P[b * 16384 + idx];
  }
  __syncthreads();
  float acc[16];
#pragma unroll
  for (int i = 0; i < 16; ++i) acc[i] = 0.f;
  for (int i = 0; i < 16; ++i) {
    const int l = half * 64 + lg + 4 * i;
    const float* frow = &F[l * BNT + b * 256];
    float a = 0.f;
#pragma unroll 8
    for (int nq = 0; nq < 64; ++nq) {
      const float4 f4 = *(const float4*)&frow[nq << 2];
      const float4 p4 = *(const float4*)&ps[m * 256 + ((nq ^ (m & 7)) << 2)];
      a = fmaf(f4.x, p4.x, a);
      a = fmaf(f4.y, p4.y, a);
      a = fmaf(f4.z, p4.z, a);
      a = fmaf(f4.w, p4.w, a);
    }
    acc[i] = a;
  }
#pragma unroll
  for (int i = 0; i < 16; ++i) {
    const int l = half * 64 + lg + 4 * i;
    VL[b * 8192 + l * 64 + m] = acc[i];
  }
}

// ---------------- finalize: intra-norm vlad, norm tok, concat, final L2 ------
__global__ __launch_bounds__(256) void finalize_kernel(
    const float* __restrict__ TK, const float* __restrict__ VL,
    float* __restrict__ out) {
  const int b = blockIdx.x, tid = threadIdx.x;
  const int lane = tid & 63, wave = tid >> 6;
  __shared__ float sred[4];
  __shared__ float ssm_part[4][64];
  __shared__ float invm_s[64];
  __shared__ float totals[1];
  const float* vl = &VL[b * 8192];
  // per-cluster (m) sum of squares over l; element idx = l*64+m, m = tid&63
  float accv = 0.f;
  for (int k = 0; k < 32; ++k) {
    const float xv = vl[tid + 256 * k];
    accv = fmaf(xv, xv, accv);
  }
  ssm_part[wave][lane] = accv;
  // token sum of squares
  const float tv = TK[b * 256 + tid];
  float ss = tv * tv;
#pragma unroll
  for (int off = 32; off; off >>= 1) ss += __shfl_down(ss, off);
  if (lane == 0) sred[wave] = ss;
  __syncthreads();
  const float sstok = sred[0] + sred[1] + sred[2] + sred[3];
  const float invtok = 1.f / fmaxf(sqrtf(sstok), 1e-12f);
  float tpart = 0.f;
  if (wave == 0) {  // tid<64
    const float s4 = ssm_part[0][tid] + ssm_part[1][tid] + ssm_part[2][tid] +
                     ssm_part[3][tid];
    const float inv = 1.f / fmaxf(sqrtf(s4), 1e-12f);
    invm_s[tid] = inv;
    tpart = s4 * inv * inv;
#pragma unroll
    for (int off = 32; off; off >>= 1) tpart += __shfl_down(tpart, off);
    if (lane == 0) totals[0] = tpart;
  }
  __syncthreads();
  const float total = totals[0] + sstok * invtok * invtok;
  const float invT = 1.f / fmaxf(sqrtf(total), 1e-12f);
  float* ob = &out[b * 8448];
  ob[tid] = tv * invtok * invT;
  for (int k = 0; k < 32; ++k) {
    const int idx = tid + 256 * k;
    ob[256 + idx] = vl[idx] * invm_s[idx & 63] * invT;
  }
}

extern "C" void kernel_launch(void* const* d_in, const int* in_sizes, int n_in,
                              void* d_out, int out_size, void* d_ws,
                              size_t ws_size, hipStream_t stream) {
  const float* x = (const float*)d_in[0];
  const float* t = (const float*)d_in[1];
  const float* Wt1 = (const float*)d_in[2];
  const float* bt1 = (const float*)d_in[3];
  const float* Wt2 = (const float*)d_in[4];
  const float* bt2 = (const float*)d_in[5];
  const float* Wc1 = (const float*)d_in[6];
  const float* bc1 = (const float*)d_in[7];
  const float* Wc2 = (const float*)d_in[8];
  const float* bc2 = (const float*)d_in[9];
  const float* Ws1 = (const float*)d_in[10];
  const float* bs1 = (const float*)d_in[11];
  const float* Ws2 = (const float*)d_in[12];
  const float* bs2 = (const float*)d_in[13];
  const float* dust = (const float*)d_in[14];
  float* out = (float*)d_out;

  // workspace layout (floats): H reused for cluster then score hidden.
  float* ws = (float*)d_ws;
  float* H = ws;                    // 512*16384
  float* F = H + 512 * BNT;         // 128*16384
  float* Sb = F + 128 * BNT;        // 64*16384
  float* P = Sb + 64 * BNT;         // 64*64*256
  float* VL = P + 64 * 16384;       // 64*8192
  float* TK = VL + 64 * 8192;       // 64*256
  // total ~52.5 MB

  token_kernel<<<64, 256, 0, stream>>>(t, Wt1, bt1, Wt2, bt2, TK);
  gemm_tile<true, true><<<dim3(256, 8), 256, 0, stream>>>(Wc1, x, bc1, H, 1536);
  gemm_tile<false, false><<<dim3(256, 2), 256, 0, stream>>>(Wc2, H, bc2, F, 512);
  gemm_tile<true, true><<<dim3(256, 8), 256, 0, stream>>>(Ws1, x, bs1, H, 1536);
  gemm_tile<false, false><<<dim3(256, 1), 256, 0, stream>>>(Ws2, H, bs2, Sb, 512);
  sinkhorn_kernel<<<64, 256, 0, stream>>>(Sb, dust, P);
  vlad_kernel<<<dim3(64, 2), 256, 0, stream>>>(F, P, VL);
  finalize_kernel<<<64, 256, 0, stream>>>(TK, VL, out);
}

// Round 3
// 398.855 us; speedup vs baseline: 4.3302x; 4.3302x over previous
//
#include <hip/hip_runtime.h>
#include <math.h>

// SALAD head. B=64, C=1536, N=256, HID=512, L=128, M=64, G=256. BNT = B*N.
#define BNT 16384

using f32x4 = __attribute__((ext_vector_type(4))) float;
using s16x8 = __attribute__((ext_vector_type(8))) short;

__device__ __forceinline__ unsigned short f32_to_bf16_rne(float f) {
  unsigned int u = __float_as_uint(f);
  u += 0x7FFFu + ((u >> 16) & 1u);
  return (unsigned short)(u >> 16);
}

__device__ __forceinline__ void gload_lds16(const ushort* g, ushort* lds) {
  __builtin_amdgcn_global_load_lds(
      (const __attribute__((address_space(1))) unsigned int*)g,
      (__attribute__((address_space(3))) unsigned int*)lds, 16, 0, 0);
}

// ---------------- token MLP layer 1: Hh[b][u] = relu(t[b]·Wt1[u] + bt1) -----
__global__ __launch_bounds__(256) void token_l1(
    const float* __restrict__ t, const float* __restrict__ Wt1,
    const float* __restrict__ bt1, float* __restrict__ Hh) {
  const int b = blockIdx.x, uc = blockIdx.y;  // grid (64, 8)
  const int tid = threadIdx.x, lane = tid & 63, wave = tid >> 6;
  __shared__ float tb[1536];
  for (int i = tid; i < 1536; i += 256) tb[i] = t[b * 1536 + i];
  __syncthreads();
  const int u0 = uc * 64;
  for (int u = u0 + wave; u < u0 + 64; u += 4) {
    const float* wr_ = &Wt1[u * 1536];
    float a = 0.f;
    for (int c = lane; c < 1536; c += 64) a = fmaf(wr_[c], tb[c], a);
#pragma unroll
    for (int off = 32; off; off >>= 1) a += __shfl_down(a, off);
    if (lane == 0) Hh[b * 512 + u] = fmaxf(a + bt1[u], 0.f);
  }
}

// ---------------- token MLP layer 2: TK[b][g] = Hh[b]·Wt2[g] + bt2 ----------
__global__ __launch_bounds__(256) void token_l2(
    const float* __restrict__ Hh, const float* __restrict__ Wt2,
    const float* __restrict__ bt2, float* __restrict__ TK) {
  const int b = blockIdx.x, gc = blockIdx.y;  // grid (64, 4)
  const int tid = threadIdx.x, lane = tid & 63, wave = tid >> 6;
  __shared__ float hb[512];
  for (int i = tid; i < 512; i += 256) hb[i] = Hh[b * 512 + i];
  __syncthreads();
  const int g0 = gc * 64;
  for (int g = g0 + wave; g < g0 + 64; g += 4) {
    const float* wr_ = &Wt2[g * 512];
    float a = 0.f;
    for (int c = lane; c < 512; c += 64) a = fmaf(wr_[c], hb[c], a);
#pragma unroll
    for (int off = 32; off; off >>= 1) a += __shfl_down(a, off);
    if (lane == 0) TK[b * 256 + g] = a + bt2[g];
  }
}

// ---------------- fp32 -> bf16 weight convert (vectorized) ------------------
__global__ __launch_bounds__(256) void convert_w_bf16(
    const float* __restrict__ W, ushort* __restrict__ Wb, int n4) {
  const int i = blockIdx.x * 256 + threadIdx.x;
  if (i < n4) {
    const float4 v = ((const float4*)W)[i];
    uint2 o;
    o.x = (unsigned)f32_to_bf16_rne(v.x) | ((unsigned)f32_to_bf16_rne(v.y) << 16);
    o.y = (unsigned)f32_to_bf16_rne(v.z) | ((unsigned)f32_to_bf16_rne(v.w) << 16);
    ((uint2*)Wb)[i] = o;
  }
}

// ------- x [64][1536][256] fp32 -> XT [16384][1536] bf16 (transpose) --------
__global__ __launch_bounds__(256) void transpose_x_bf16(
    const float* __restrict__ x, ushort* __restrict__ XT) {
  const int cc = blockIdx.x * 64;  // channel chunk (24)
  const int b = blockIdx.y;        // 64
  const int n = threadIdx.x;       // 256
  const float* src = x + b * 393216 + cc * 256 + n;
  ushort* dst = XT + (b * 256 + n) * 1536 + cc;
#pragma unroll
  for (int g = 0; g < 8; ++g) {
    float v[8];
#pragma unroll
    for (int j = 0; j < 8; ++j) v[j] = src[(g * 8 + j) * 256];  // coalesced
    uint4 o;
    o.x = (unsigned)f32_to_bf16_rne(v[0]) | ((unsigned)f32_to_bf16_rne(v[1]) << 16);
    o.y = (unsigned)f32_to_bf16_rne(v[2]) | ((unsigned)f32_to_bf16_rne(v[3]) << 16);
    o.z = (unsigned)f32_to_bf16_rne(v[4]) | ((unsigned)f32_to_bf16_rne(v[5]) << 16);
    o.w = (unsigned)f32_to_bf16_rne(v[6]) | ((unsigned)f32_to_bf16_rne(v[7]) << 16);
    *(uint4*)(dst + g * 8) = o;
  }
}

// ---- MFMA GEMM: C[512][16384] = relu(A[512][1536] @ XT^T + bias) -----------
// A bf16 [512][1536] row-major; Bt = XT bf16 [16384][1536] (token-major, k-contig).
// 128x128 tile, BK=32, 4 waves (2x2), per-wave 64x64 = 4x4 frags of 16x16x32.
__global__ __launch_bounds__(256) void gemm1_mfma(
    const ushort* __restrict__ A, const ushort* __restrict__ Bt,
    const float* __restrict__ bias, float* __restrict__ Cout) {
  constexpr int K = 1536;
  __shared__ ushort As[128 * 32];
  __shared__ ushort Bs[128 * 32];
  const int tid = threadIdx.x;
  const int l = tid & 63, w = tid >> 6;
  const int m0 = blockIdx.y * 128, n0 = blockIdx.x * 128;
  const int wr = w >> 1, wc = w & 1;
  const int lr = l & 15, kq = l >> 4;

  f32x4 acc[4][4];
#pragma unroll
  for (int mi = 0; mi < 4; ++mi)
#pragma unroll
    for (int ni = 0; ni < 4; ++ni) acc[mi][ni] = (f32x4){0.f, 0.f, 0.f, 0.f};

  // staging: 16B chunk c in [0,512): tile-row r=c>>2, k-oct q=c&3; LDS byte c*16
  const int rA0 = tid >> 2;             // chunk tid
  const int q8 = (tid & 3) * 8;         // k element offset within BK
  ushort* AsW0 = As + (w * 64) * 8;     // wave-uniform LDS bases (ushort units)
  ushort* AsW1 = As + (256 + w * 64) * 8;
  ushort* BsW0 = Bs + (w * 64) * 8;
  ushort* BsW1 = Bs + (256 + w * 64) * 8;
  const ushort* Arow0 = A + (m0 + rA0) * K + q8;
  const ushort* Arow1 = A + (m0 + rA0 + 64) * K + q8;
  const ushort* Brow0 = Bt + (n0 + rA0) * K + q8;
  const ushort* Brow1 = Bt + (n0 + rA0 + 64) * K + q8;

  for (int k0 = 0; k0 < K; k0 += 32) {
    __syncthreads();
    gload_lds16(Arow0 + k0, AsW0);
    gload_lds16(Arow1 + k0, AsW1);
    gload_lds16(Brow0 + k0, BsW0);
    gload_lds16(Brow1 + k0, BsW1);
    __syncthreads();
    s16x8 af[4], bfr[4];
#pragma unroll
    for (int mi = 0; mi < 4; ++mi)
      af[mi] = *(const s16x8*)(As + (wr * 64 + mi * 16 + lr) * 32 + kq * 8);
#pragma unroll
    for (int ni = 0; ni < 4; ++ni)
      bfr[ni] = *(const s16x8*)(Bs + (wc * 64 + ni * 16 + lr) * 32 + kq * 8);
#pragma unroll
    for (int mi = 0; mi < 4; ++mi)
#pragma unroll
      for (int ni = 0; ni < 4; ++ni)
        acc[mi][ni] = __builtin_amdgcn_mfma_f32_16x16x32_bf16(
            af[mi], bfr[ni], acc[mi][ni], 0, 0, 0);
  }

  // epilogue: C row = m0+wr*64+mi*16+kq*4+j, col = n0+wc*64+ni*16+lr
#pragma unroll
  for (int mi = 0; mi < 4; ++mi) {
    const int rbase = m0 + wr * 64 + mi * 16 + kq * 4;
    float b4[4];
#pragma unroll
    for (int j = 0; j < 4; ++j) b4[j] = bias[rbase + j];
#pragma unroll
    for (int ni = 0; ni < 4; ++ni) {
      const int col = n0 + wc * 64 + ni * 16 + lr;
      float* cr = Cout + (size_t)rbase * BNT + col;
#pragma unroll
      for (int j = 0; j < 4; ++j)
        cr[(size_t)j * BNT] = fmaxf(acc[mi][ni][j] + b4[j], 0.f);
    }
  }
}

// ---------------- fp32 tiled GEMM (second layers + fallback) ----------------
template <bool XVIEW, bool RELU>
__global__ __launch_bounds__(256) void gemm_tile(
    const float* __restrict__ A, const float* __restrict__ Bsrc,
    const float* __restrict__ bias, float* __restrict__ Cout, int K) {
  __shared__ float As[16][68];
  __shared__ float Bsh[16][68];
  const int tid = threadIdx.x;
  const int tx = tid & 15, ty = tid >> 4;
  const int rowBase = blockIdx.y * 64;
  const int colBase = blockIdx.x * 64;
  const int bb = colBase >> 8, n0 = colBase & 255;
  const int boff = XVIEW ? (bb * 393216 + n0) : colBase;
  const int la_row = tid >> 2, la_kq = (tid & 3) << 2;
  const int lb_k = tid >> 4, lb_c = (tid & 15) << 2;

  float acc[4][4];
#pragma unroll
  for (int r = 0; r < 4; ++r)
#pragma unroll
    for (int c = 0; c < 4; ++c) acc[r][c] = 0.f;

  for (int k0 = 0; k0 < K; k0 += 16) {
    const float4 av = *(const float4*)&A[(rowBase + la_row) * K + k0 + la_kq];
    float4 bv;
    if (XVIEW)
      bv = *(const float4*)&Bsrc[boff + (k0 + lb_k) * 256 + lb_c];
    else
      bv = *(const float4*)&Bsrc[(k0 + lb_k) * BNT + boff + lb_c];
    As[la_kq + 0][la_row] = av.x;
    As[la_kq + 1][la_row] = av.y;
    As[la_kq + 2][la_row] = av.z;
    As[la_kq + 3][la_row] = av.w;
    *(float4*)&Bsh[lb_k][lb_c] = bv;
    __syncthreads();
#pragma unroll
    for (int kk = 0; kk < 16; ++kk) {
      const float4 a4 = *(const float4*)&As[kk][ty << 2];
      const float4 b4 = *(const float4*)&Bsh[kk][tx << 2];
      acc[0][0] = fmaf(a4.x, b4.x, acc[0][0]);
      acc[0][1] = fmaf(a4.x, b4.y, acc[0][1]);
      acc[0][2] = fmaf(a4.x, b4.z, acc[0][2]);
      acc[0][3] = fmaf(a4.x, b4.w, acc[0][3]);
      acc[1][0] = fmaf(a4.y, b4.x, acc[1][0]);
      acc[1][1] = fmaf(a4.y, b4.y, acc[1][1]);
      acc[1][2] = fmaf(a4.y, b4.z, acc[1][2]);
      acc[1][3] = fmaf(a4.y, b4.w, acc[1][3]);
      acc[2][0] = fmaf(a4.z, b4.x, acc[2][0]);
      acc[2][1] = fmaf(a4.z, b4.y, acc[2][1]);
      acc[2][2] = fmaf(a4.z, b4.z, acc[2][2]);
      acc[2][3] = fmaf(a4.z, b4.w, acc[2][3]);
      acc[3][0] = fmaf(a4.w, b4.x, acc[3][0]);
      acc[3][1] = fmaf(a4.w, b4.y, acc[3][1]);
      acc[3][2] = fmaf(a4.w, b4.z, acc[3][2]);
      acc[3][3] = fmaf(a4.w, b4.w, acc[3][3]);
    }
    __syncthreads();
  }
#pragma unroll
  for (int r = 0; r < 4; ++r) {
    const int row = rowBase + (ty << 2) + r;
    const float bsv = bias[row];
    float4 o;
    o.x = acc[r][0] + bsv;
    o.y = acc[r][1] + bsv;
    o.z = acc[r][2] + bsv;
    o.w = acc[r][3] + bsv;
    if (RELU) {
      o.x = fmaxf(o.x, 0.f);
      o.y = fmaxf(o.y, 0.f);
      o.z = fmaxf(o.z, 0.f);
      o.w = fmaxf(o.w, 0.f);
    }
    *(float4*)&Cout[row * BNT + colBase + (tx << 2)] = o;
  }
}

// ---------------- Sinkhorn (log domain, 3 iters, dustbin row) ----------------
__global__ __launch_bounds__(256) void sinkhorn_kernel(
    const float* __restrict__ S, const float* __restrict__ dustp,
    float* __restrict__ P) {
  const int b = blockIdx.x, tid = threadIdx.x;
  const int lane = tid & 63, wave = tid >> 6;
  __shared__ float Ms[65][256];
  __shared__ float u[65];
  __shared__ float v[256];
  const float dust = dustp[0];
  for (int idx = tid; idx < 16384; idx += 256) {
    const int m = idx >> 8, n = idx & 255;
    Ms[m][n] = S[m * BNT + b * 256 + n];
  }
  Ms[64][tid] = dust;
  v[tid] = 0.f;
  if (tid < 65) u[tid] = 0.f;
  const float norm = -logf(320.f);
  const float la_dust = norm + logf(192.f);
  __syncthreads();
  for (int it = 0; it < 3; ++it) {
    for (int i = wave; i < 65; i += 4) {
      const float x0 = Ms[i][lane] + v[lane];
      const float x1 = Ms[i][lane + 64] + v[lane + 64];
      const float x2 = Ms[i][lane + 128] + v[lane + 128];
      const float x3 = Ms[i][lane + 192] + v[lane + 192];
      float mm = fmaxf(fmaxf(x0, x1), fmaxf(x2, x3));
#pragma unroll
      for (int off = 32; off; off >>= 1) mm = fmaxf(mm, __shfl_xor(mm, off));
      float s = expf(x0 - mm) + expf(x1 - mm) + expf(x2 - mm) + expf(x3 - mm);
#pragma unroll
      for (int off = 32; off; off >>= 1) s += __shfl_xor(s, off);
      if (lane == 0) u[i] = (i == 64 ? la_dust : norm) - (logf(s) + mm);
    }
    __syncthreads();
    {
      const int n = tid;
      float mm = -1e30f;
      for (int i = 0; i < 65; ++i) mm = fmaxf(mm, Ms[i][n] + u[i]);
      float s = 0.f;
      for (int i = 0; i < 65; ++i) s += expf(Ms[i][n] + u[i] - mm);
      v[n] = norm - (logf(s) + mm);
    }
    __syncthreads();
  }
  for (int idx = tid; idx < 16384; idx += 256) {
    const int m = idx >> 8, n = idx & 255;
    P[b * 16384 + idx] = expf(Ms[m][n] + u[m] + v[n] - norm);
  }
}

// ---------------- VLAD ------------------------------------------------------
__device__ __forceinline__ int ps_idx(int m, int n) {
  return m * 256 + ((((n >> 2) ^ (m & 7)) << 2) | (n & 3));
}
__global__ __launch_bounds__(256) void vlad_kernel(const float* __restrict__ F,
                                                   const float* __restrict__ P,
                                                   float* __restrict__ VL) {
  const int b = blockIdx.x, half = blockIdx.y;
  const int tid = threadIdx.x;
  const int m = tid & 63, lg = tid >> 6;
  __shared__ float ps[64 * 256];
  for (int idx = tid; idx < 16384; idx += 256) {
    const int mm = idx >> 8, n = idx & 255;
    ps[ps_idx(mm, n)] = P[b * 16384 + idx];
  }
  __syncthreads();
  float acc[16];
#pragma unroll
  for (int i = 0; i < 16; ++i) acc[i] = 0.f;
  for (int i = 0; i < 16; ++i) {
    const int ll = half * 64 + lg + 4 * i;
    const float* frow = &F[ll * BNT + b * 256];
    float a = 0.f;
#pragma unroll 8
    for (int nq = 0; nq < 64; ++nq) {
      const float4 f4 = *(const float4*)&frow[nq << 2];
      const float4 p4 = *(const float4*)&ps[m * 256 + ((nq ^ (m & 7)) << 2)];
      a = fmaf(f4.x, p4.x, a);
      a = fmaf(f4.y, p4.y, a);
      a = fmaf(f4.z, p4.z, a);
      a = fmaf(f4.w, p4.w, a);
    }
    acc[i] = a;
  }
#pragma unroll
  for (int i = 0; i < 16; ++i) {
    const int ll = half * 64 + lg + 4 * i;
    VL[b * 8192 + ll * 64 + m] = acc[i];
  }
}

// ---------------- finalize ---------------------------------------------------
__global__ __launch_bounds__(256) void finalize_kernel(
    const float* __restrict__ TK, const float* __restrict__ VL,
    float* __restrict__ out) {
  const int b = blockIdx.x, tid = threadIdx.x;
  const int lane = tid & 63, wave = tid >> 6;
  __shared__ float sred[4];
  __shared__ float ssm_part[4][64];
  __shared__ float invm_s[64];
  __shared__ float totals[1];
  const float* vl = &VL[b * 8192];
  float accv = 0.f;
  for (int k = 0; k < 32; ++k) {
    const float xv = vl[tid + 256 * k];
    accv = fmaf(xv, xv, accv);
  }
  ssm_part[wave][lane] = accv;
  const float tv = TK[b * 256 + tid];
  float ss = tv * tv;
#pragma unroll
  for (int off = 32; off; off >>= 1) ss += __shfl_down(ss, off);
  if (lane == 0) sred[wave] = ss;
  __syncthreads();
  const float sstok = sred[0] + sred[1] + sred[2] + sred[3];
  const float invtok = 1.f / fmaxf(sqrtf(sstok), 1e-12f);
  float tpart = 0.f;
  if (wave == 0) {
    const float s4 = ssm_part[0][tid] + ssm_part[1][tid] + ssm_part[2][tid] +
                     ssm_part[3][tid];
    const float inv = 1.f / fmaxf(sqrtf(s4), 1e-12f);
    invm_s[tid] = inv;
    tpart = s4 * inv * inv;
#pragma unroll
    for (int off = 32; off; off >>= 1) tpart += __shfl_down(tpart, off);
    if (lane == 0) totals[0] = tpart;
  }
  __syncthreads();
  const float total = totals[0] + sstok * invtok * invtok;
  const float invT = 1.f / fmaxf(sqrtf(total), 1e-12f);
  float* ob = &out[b * 8448];
  ob[tid] = tv * invtok * invT;
  for (int k = 0; k < 32; ++k) {
    const int idx = tid + 256 * k;
    ob[256 + idx] = vl[idx] * invm_s[idx & 63] * invT;
  }
}

extern "C" void kernel_launch(void* const* d_in, const int* in_sizes, int n_in,
                              void* d_out, int out_size, void* d_ws,
                              size_t ws_size, hipStream_t stream) {
  const float* x = (const float*)d_in[0];
  const float* t = (const float*)d_in[1];
  const float* Wt1 = (const float*)d_in[2];
  const float* bt1 = (const float*)d_in[3];
  const float* Wt2 = (const float*)d_in[4];
  const float* bt2 = (const float*)d_in[5];
  const float* Wc1 = (const float*)d_in[6];
  const float* bc1 = (const float*)d_in[7];
  const float* Wc2 = (const float*)d_in[8];
  const float* bc2 = (const float*)d_in[9];
  const float* Ws1 = (const float*)d_in[10];
  const float* bs1 = (const float*)d_in[11];
  const float* Ws2 = (const float*)d_in[12];
  const float* bs2 = (const float*)d_in[13];
  const float* dust = (const float*)d_in[14];
  float* out = (float*)d_out;

  if (ws_size >= 97714176ull) {
    // bf16 MFMA path. Byte layout (F aliases XT, which is dead before F is
    // written; all kernels stream-ordered).
    char* base = (char*)d_ws;
    ushort* XT = (ushort*)base;                     // 16384x1536 bf16 (50.3MB)
    float* F = (float*)base;                        // alias, 128xBNT f32
    float* H = (float*)(base + 50331648);           // 512xBNT f32
    float* Sb = (float*)(base + 83886080);          // 64xBNT
    float* P = (float*)(base + 88080384);           // 64x16384
    float* VL = (float*)(base + 92274688);          // 64x8192
    float* TK = (float*)(base + 94371840);          // 64x256
    float* Hh = (float*)(base + 94437376);          // 64x512
    ushort* Wc1b = (ushort*)(base + 94568448);      // 512x1536 bf16
    ushort* Ws1b = (ushort*)(base + 96141312);      // 512x1536 bf16

    token_l1<<<dim3(64, 8), 256, 0, stream>>>(t, Wt1, bt1, Hh);
    token_l2<<<dim3(64, 4), 256, 0, stream>>>(Hh, Wt2, bt2, TK);
    convert_w_bf16<<<768, 256, 0, stream>>>(Wc1, Wc1b, 196608);
    convert_w_bf16<<<768, 256, 0, stream>>>(Ws1, Ws1b, 196608);
    transpose_x_bf16<<<dim3(24, 64), 256, 0, stream>>>(x, XT);
    // score branch first (so XT dies before F overwrites it)
    gemm1_mfma<<<dim3(128, 4), 256, 0, stream>>>(Ws1b, XT, bs1, H);
    gemm_tile<false, false><<<dim3(256, 1), 256, 0, stream>>>(Ws2, H, bs2, Sb, 512);
    sinkhorn_kernel<<<64, 256, 0, stream>>>(Sb, dust, P);
    // cluster branch
    gemm1_mfma<<<dim3(128, 4), 256, 0, stream>>>(Wc1b, XT, bc1, H);
    gemm_tile<false, false><<<dim3(256, 2), 256, 0, stream>>>(Wc2, H, bc2, F, 512);
    vlad_kernel<<<dim3(64, 2), 256, 0, stream>>>(F, P, VL);
    finalize_kernel<<<64, 256, 0, stream>>>(TK, VL, out);
  } else {
    // fp32 fallback (fits 52.6 MB)
    float* ws = (float*)d_ws;
    float* H = ws;                  // 512*BNT
    float* F = H + 512 * BNT;       // 128*BNT
    float* Sb = F + 128 * BNT;      // 64*BNT
    float* P = Sb + 64 * BNT;       // 64*16384
    float* VL = P + 64 * BNT;       // 64*8192
    float* TK = VL + 64 * 8192;     // 64*256
    float* Hh = P;                  // alias: token done before sinkhorn writes P

    token_l1<<<dim3(64, 8), 256, 0, stream>>>(t, Wt1, bt1, Hh);
    token_l2<<<dim3(64, 4), 256, 0, stream>>>(Hh, Wt2, bt2, TK);
    gemm_tile<true, true><<<dim3(256, 8), 256, 0, stream>>>(Wc1, x, bc1, H, 1536);
    gemm_tile<false, false><<<dim3(256, 2), 256, 0, stream>>>(Wc2, H, bc2, F, 512);
    gemm_tile<true, true><<<dim3(256, 8), 256, 0, stream>>>(Ws1, x, bs1, H, 1536);
    gemm_tile<false, false><<<dim3(256, 1), 256, 0, stream>>>(Ws2, H, bs2, Sb, 512);
    sinkhorn_kernel<<<64, 256, 0, stream>>>(Sb, dust, P);
    vlad_kernel<<<dim3(64, 2), 256, 0, stream>>>(F, P, VL);
    finalize_kernel<<<64, 256, 0, stream>>>(TK, VL, out);
  }
}

// Round 4
// 351.738 us; speedup vs baseline: 4.9102x; 1.1340x over previous
//
#include <hip/hip_runtime.h>
#include <math.h>

// SALAD head. B=64, C=1536, N=256, HID=512, L=128, M=64, G=256. BNT = B*N.
#define BNT 16384

using f32x4 = __attribute__((ext_vector_type(4))) float;
using s16x8 = __attribute__((ext_vector_type(8))) short;

__device__ __forceinline__ unsigned short f32_to_bf16_rne(float f) {
  unsigned int u = __float_as_uint(f);
  u += 0x7FFFu + ((u >> 16) & 1u);
  return (unsigned short)(u >> 16);
}
__device__ __forceinline__ unsigned pack_bf16x2(float a, float b) {
  return (unsigned)f32_to_bf16_rne(a) | ((unsigned)f32_to_bf16_rne(b) << 16);
}

__device__ __forceinline__ void gload_lds16(const ushort* g, ushort* lds) {
  __builtin_amdgcn_global_load_lds(
      (const __attribute__((address_space(1))) unsigned int*)g,
      (__attribute__((address_space(3))) unsigned int*)lds, 16, 0, 0);
}

// ---- small fp32 GEMM, both operands row-major K-contiguous -----------------
// C[64][Nn] = act(A[64][K] @ Bw[Nn][K]^T + bias[n]);  grid.x = Nn/64.
template <bool RELU>
__global__ __launch_bounds__(256) void gemm_tt(
    const float* __restrict__ A, const float* __restrict__ Bw,
    const float* __restrict__ bias, float* __restrict__ C, int K, int Nn) {
  __shared__ float As[16][68];  // As[k][m]
  __shared__ float Bs[16][68];  // Bs[k][n]
  const int tid = threadIdx.x;
  const int tx = tid & 15, ty = tid >> 4;
  const int n0 = blockIdx.x * 64;
  const int lrow = tid >> 2, lkq = (tid & 3) << 2;

  float acc[4][4];
#pragma unroll
  for (int r = 0; r < 4; ++r)
#pragma unroll
    for (int c = 0; c < 4; ++c) acc[r][c] = 0.f;

  for (int k0 = 0; k0 < K; k0 += 16) {
    const float4 av = *(const float4*)&A[lrow * K + k0 + lkq];
    const float4 bv = *(const float4*)&Bw[(n0 + lrow) * K + k0 + lkq];
    As[lkq + 0][lrow] = av.x;
    As[lkq + 1][lrow] = av.y;
    As[lkq + 2][lrow] = av.z;
    As[lkq + 3][lrow] = av.w;
    Bs[lkq + 0][lrow] = bv.x;
    Bs[lkq + 1][lrow] = bv.y;
    Bs[lkq + 2][lrow] = bv.z;
    Bs[lkq + 3][lrow] = bv.w;
    __syncthreads();
#pragma unroll
    for (int kk = 0; kk < 16; ++kk) {
      const float4 a4 = *(const float4*)&As[kk][ty << 2];
      const float4 b4 = *(const float4*)&Bs[kk][tx << 2];
      acc[0][0] = fmaf(a4.x, b4.x, acc[0][0]);
      acc[0][1] = fmaf(a4.x, b4.y, acc[0][1]);
      acc[0][2] = fmaf(a4.x, b4.z, acc[0][2]);
      acc[0][3] = fmaf(a4.x, b4.w, acc[0][3]);
      acc[1][0] = fmaf(a4.y, b4.x, acc[1][0]);
      acc[1][1] = fmaf(a4.y, b4.y, acc[1][1]);
      acc[1][2] = fmaf(a4.y, b4.z, acc[1][2]);
      acc[1][3] = fmaf(a4.y, b4.w, acc[1][3]);
      acc[2][0] = fmaf(a4.z, b4.x, acc[2][0]);
      acc[2][1] = fmaf(a4.z, b4.y, acc[2][1]);
      acc[2][2] = fmaf(a4.z, b4.z, acc[2][2]);
      acc[2][3] = fmaf(a4.z, b4.w, acc[2][3]);
      acc[3][0] = fmaf(a4.w, b4.x, acc[3][0]);
      acc[3][1] = fmaf(a4.w, b4.y, acc[3][1]);
      acc[3][2] = fmaf(a4.w, b4.z, acc[3][2]);
      acc[3][3] = fmaf(a4.w, b4.w, acc[3][3]);
    }
    __syncthreads();
  }
#pragma unroll
  for (int r = 0; r < 4; ++r) {
    const int row = (ty << 2) + r;
    float4 o;
    o.x = acc[r][0] + bias[n0 + (tx << 2) + 0];
    o.y = acc[r][1] + bias[n0 + (tx << 2) + 1];
    o.z = acc[r][2] + bias[n0 + (tx << 2) + 2];
    o.w = acc[r][3] + bias[n0 + (tx << 2) + 3];
    if (RELU) {
      o.x = fmaxf(o.x, 0.f);
      o.y = fmaxf(o.y, 0.f);
      o.z = fmaxf(o.z, 0.f);
      o.w = fmaxf(o.w, 0.f);
    }
    *(float4*)&C[row * Nn + n0 + (tx << 2)] = o;
  }
}

// ---------------- fp32 -> bf16 weight convert (vectorized) ------------------
__global__ __launch_bounds__(256) void convert_w_bf16(
    const float* __restrict__ W, ushort* __restrict__ Wb, int n4) {
  const int i = blockIdx.x * 256 + threadIdx.x;
  if (i < n4) {
    const float4 v = ((const float4*)W)[i];
    uint2 o;
    o.x = pack_bf16x2(v.x, v.y);
    o.y = pack_bf16x2(v.z, v.w);
    ((uint2*)Wb)[i] = o;
  }
}

// ------- x [64][1536][256] fp32 -> XT [16384][1536] bf16 (transpose) --------
__global__ __launch_bounds__(256) void transpose_x_bf16(
    const float* __restrict__ x, ushort* __restrict__ XT) {
  const int cc = blockIdx.x * 64;
  const int b = blockIdx.y;
  const int n = threadIdx.x;
  const float* src = x + b * 393216 + cc * 256 + n;
  ushort* dst = XT + (b * 256 + n) * 1536 + cc;
#pragma unroll
  for (int g = 0; g < 8; ++g) {
    float v[8];
#pragma unroll
    for (int j = 0; j < 8; ++j) v[j] = src[(g * 8 + j) * 256];
    uint4 o;
    o.x = pack_bf16x2(v[0], v[1]);
    o.y = pack_bf16x2(v[2], v[3]);
    o.z = pack_bf16x2(v[4], v[5]);
    o.w = pack_bf16x2(v[6], v[7]);
    *(uint4*)(dst + g * 8) = o;
  }
}

// ---- layer-1 MFMA GEMM: HT[j][hbase+h] = bf16(relu(A[h]·XT[j] + bias)) -----
// A bf16 [512][1536]; Bt = XT [16384][1536]. 128x128 tile, BK=32, 4 waves.
__global__ __launch_bounds__(256) void gemm1_mfma(
    const ushort* __restrict__ A, const ushort* __restrict__ Bt,
    const float* __restrict__ bias, ushort* __restrict__ HT, int hbase) {
  constexpr int K = 1536;
  __shared__ ushort As[128 * 32];
  __shared__ ushort Bs[128 * 32];
  const int tid = threadIdx.x;
  const int l = tid & 63, w = tid >> 6;
  const int m0 = blockIdx.y * 128, n0 = blockIdx.x * 128;
  const int wr = w >> 1, wc = w & 1;
  const int lr = l & 15, kq = l >> 4;

  f32x4 acc[4][4];
#pragma unroll
  for (int mi = 0; mi < 4; ++mi)
#pragma unroll
    for (int ni = 0; ni < 4; ++ni) acc[mi][ni] = (f32x4){0.f, 0.f, 0.f, 0.f};

  const int rA0 = tid >> 2;
  const int q8 = (tid & 3) * 8;
  ushort* AsW0 = As + (w * 64) * 8;
  ushort* AsW1 = As + (256 + w * 64) * 8;
  ushort* BsW0 = Bs + (w * 64) * 8;
  ushort* BsW1 = Bs + (256 + w * 64) * 8;
  const ushort* Arow0 = A + (m0 + rA0) * K + q8;
  const ushort* Arow1 = A + (m0 + rA0 + 64) * K + q8;
  const ushort* Brow0 = Bt + (n0 + rA0) * K + q8;
  const ushort* Brow1 = Bt + (n0 + rA0 + 64) * K + q8;

  for (int k0 = 0; k0 < K; k0 += 32) {
    __syncthreads();
    gload_lds16(Arow0 + k0, AsW0);
    gload_lds16(Arow1 + k0, AsW1);
    gload_lds16(Brow0 + k0, BsW0);
    gload_lds16(Brow1 + k0, BsW1);
    __syncthreads();
    s16x8 af[4], bfr[4];
#pragma unroll
    for (int mi = 0; mi < 4; ++mi)
      af[mi] = *(const s16x8*)(As + (wr * 64 + mi * 16 + lr) * 32 + kq * 8);
#pragma unroll
    for (int ni = 0; ni < 4; ++ni)
      bfr[ni] = *(const s16x8*)(Bs + (wc * 64 + ni * 16 + lr) * 32 + kq * 8);
#pragma unroll
    for (int mi = 0; mi < 4; ++mi)
#pragma unroll
      for (int ni = 0; ni < 4; ++ni)
        acc[mi][ni] = __builtin_amdgcn_mfma_f32_16x16x32_bf16(
            af[mi], bfr[ni], acc[mi][ni], 0, 0, 0);
  }

  // C row (h) = m0+wr*64+mi*16+kq*4+j, col (token) = n0+wc*64+ni*16+lr.
  // Write bf16 transposed: HT[col][hbase + row], 4 h contiguous per store.
#pragma unroll
  for (int mi = 0; mi < 4; ++mi) {
    const int rbase = m0 + wr * 64 + mi * 16 + kq * 4;
    float b4[4];
#pragma unroll
    for (int j = 0; j < 4; ++j) b4[j] = bias[rbase + j];
#pragma unroll
    for (int ni = 0; ni < 4; ++ni) {
      const int col = n0 + wc * 64 + ni * 16 + lr;
      const float v0 = fmaxf(acc[mi][ni][0] + b4[0], 0.f);
      const float v1 = fmaxf(acc[mi][ni][1] + b4[1], 0.f);
      const float v2 = fmaxf(acc[mi][ni][2] + b4[2], 0.f);
      const float v3 = fmaxf(acc[mi][ni][3] + b4[3], 0.f);
      uint2 o;
      o.x = pack_bf16x2(v0, v1);
      o.y = pack_bf16x2(v2, v3);
      *(uint2*)(HT + (size_t)col * 1024 + hbase + rbase) = o;
    }
  }
}

// ---- layer-2 MFMA GEMM: C2[192][BNT] = A2[256][1024] @ HT^T + b2 -----------
// rows 0..127 = cluster F, 128..191 = score S, 192..255 junk (not written).
__global__ __launch_bounds__(256) void gemm2_mfma(
    const ushort* __restrict__ A2, const ushort* __restrict__ HT,
    const float* __restrict__ b2, float* __restrict__ C2) {
  constexpr int K = 1024;
  __shared__ ushort As[128 * 32];
  __shared__ ushort Bs[128 * 32];
  const int tid = threadIdx.x;
  const int l = tid & 63, w = tid >> 6;
  const int m0 = blockIdx.y * 128, n0 = blockIdx.x * 128;
  const int wr = w >> 1, wc = w & 1;
  const int lr = l & 15, kq = l >> 4;

  f32x4 acc[4][4];
#pragma unroll
  for (int mi = 0; mi < 4; ++mi)
#pragma unroll
    for (int ni = 0; ni < 4; ++ni) acc[mi][ni] = (f32x4){0.f, 0.f, 0.f, 0.f};

  const int rA0 = tid >> 2;
  const int q8 = (tid & 3) * 8;
  ushort* AsW0 = As + (w * 64) * 8;
  ushort* AsW1 = As + (256 + w * 64) * 8;
  ushort* BsW0 = Bs + (w * 64) * 8;
  ushort* BsW1 = Bs + (256 + w * 64) * 8;
  const ushort* Arow0 = A2 + (m0 + rA0) * K + q8;
  const ushort* Arow1 = A2 + (m0 + rA0 + 64) * K + q8;
  const ushort* Brow0 = HT + (size_t)(n0 + rA0) * K + q8;
  const ushort* Brow1 = HT + (size_t)(n0 + rA0 + 64) * K + q8;

  for (int k0 = 0; k0 < K; k0 += 32) {
    __syncthreads();
    gload_lds16(Arow0 + k0, AsW0);
    gload_lds16(Arow1 + k0, AsW1);
    gload_lds16(Brow0 + k0, BsW0);
    gload_lds16(Brow1 + k0, BsW1);
    __syncthreads();
    s16x8 af[4], bfr[4];
#pragma unroll
    for (int mi = 0; mi < 4; ++mi)
      af[mi] = *(const s16x8*)(As + (wr * 64 + mi * 16 + lr) * 32 + kq * 8);
#pragma unroll
    for (int ni = 0; ni < 4; ++ni)
      bfr[ni] = *(const s16x8*)(Bs + (wc * 64 + ni * 16 + lr) * 32 + kq * 8);
#pragma unroll
    for (int mi = 0; mi < 4; ++mi)
#pragma unroll
      for (int ni = 0; ni < 4; ++ni)
        acc[mi][ni] = __builtin_amdgcn_mfma_f32_16x16x32_bf16(
            af[mi], bfr[ni], acc[mi][ni], 0, 0, 0);
  }

#pragma unroll
  for (int mi = 0; mi < 4; ++mi) {
    const int rbase = m0 + wr * 64 + mi * 16 + kq * 4;
    if (rbase < 192) {
      float b4[4];
#pragma unroll
      for (int j = 0; j < 4; ++j) b4[j] = b2[rbase + j];
#pragma unroll
      for (int ni = 0; ni < 4; ++ni) {
        const int col = n0 + wc * 64 + ni * 16 + lr;
        float* cr = C2 + (size_t)rbase * BNT + col;
#pragma unroll
        for (int j = 0; j < 4; ++j) cr[(size_t)j * BNT] = acc[mi][ni][j] + b4[j];
      }
    }
  }
}

// ---- build stacked layer-2 weights: A2[256][1024] bf16, b2[256] ------------
__global__ __launch_bounds__(256) void build_A2(
    const float* __restrict__ Wc2, const float* __restrict__ Ws2,
    const float* __restrict__ bc2, const float* __restrict__ bs2,
    ushort* __restrict__ A2, float* __restrict__ b2) {
  const int r = blockIdx.x;
  const int c = threadIdx.x * 4;
  float v[4] = {0.f, 0.f, 0.f, 0.f};
  if (r < 128) {
    if (c < 512) {
#pragma unroll
      for (int j = 0; j < 4; ++j) v[j] = Wc2[r * 512 + c + j];
    }
  } else if (r < 192) {
    if (c >= 512) {
#pragma unroll
      for (int j = 0; j < 4; ++j) v[j] = Ws2[(r - 128) * 512 + (c - 512) + j];
    }
  }
  uint2 o;
  o.x = pack_bf16x2(v[0], v[1]);
  o.y = pack_bf16x2(v[2], v[3]);
  *(uint2*)(A2 + r * 1024 + c) = o;
  if (threadIdx.x == 0)
    b2[r] = r < 128 ? bc2[r] : (r < 192 ? bs2[r - 128] : 0.f);
}

// ---------------- fp32 tiled GEMM (fallback path only) ----------------------
template <bool XVIEW, bool RELU>
__global__ __launch_bounds__(256) void gemm_tile(
    const float* __restrict__ A, const float* __restrict__ Bsrc,
    const float* __restrict__ bias, float* __restrict__ Cout, int K) {
  __shared__ float As[16][68];
  __shared__ float Bsh[16][68];
  const int tid = threadIdx.x;
  const int tx = tid & 15, ty = tid >> 4;
  const int rowBase = blockIdx.y * 64;
  const int colBase = blockIdx.x * 64;
  const int bb = colBase >> 8, n0 = colBase & 255;
  const int boff = XVIEW ? (bb * 393216 + n0) : colBase;
  const int la_row = tid >> 2, la_kq = (tid & 3) << 2;
  const int lb_k = tid >> 4, lb_c = (tid & 15) << 2;

  float acc[4][4];
#pragma unroll
  for (int r = 0; r < 4; ++r)
#pragma unroll
    for (int c = 0; c < 4; ++c) acc[r][c] = 0.f;

  for (int k0 = 0; k0 < K; k0 += 16) {
    const float4 av = *(const float4*)&A[(rowBase + la_row) * K + k0 + la_kq];
    float4 bv;
    if (XVIEW)
      bv = *(const float4*)&Bsrc[boff + (k0 + lb_k) * 256 + lb_c];
    else
      bv = *(const float4*)&Bsrc[(k0 + lb_k) * BNT + boff + lb_c];
    As[la_kq + 0][la_row] = av.x;
    As[la_kq + 1][la_row] = av.y;
    As[la_kq + 2][la_row] = av.z;
    As[la_kq + 3][la_row] = av.w;
    *(float4*)&Bsh[lb_k][lb_c] = bv;
    __syncthreads();
#pragma unroll
    for (int kk = 0; kk < 16; ++kk) {
      const float4 a4 = *(const float4*)&As[kk][ty << 2];
      const float4 b4 = *(const float4*)&Bsh[kk][tx << 2];
      acc[0][0] = fmaf(a4.x, b4.x, acc[0][0]);
      acc[0][1] = fmaf(a4.x, b4.y, acc[0][1]);
      acc[0][2] = fmaf(a4.x, b4.z, acc[0][2]);
      acc[0][3] = fmaf(a4.x, b4.w, acc[0][3]);
      acc[1][0] = fmaf(a4.y, b4.x, acc[1][0]);
      acc[1][1] = fmaf(a4.y, b4.y, acc[1][1]);
      acc[1][2] = fmaf(a4.y, b4.z, acc[1][2]);
      acc[1][3] = fmaf(a4.y, b4.w, acc[1][3]);
      acc[2][0] = fmaf(a4.z, b4.x, acc[2][0]);
      acc[2][1] = fmaf(a4.z, b4.y, acc[2][1]);
      acc[2][2] = fmaf(a4.z, b4.z, acc[2][2]);
      acc[2][3] = fmaf(a4.z, b4.w, acc[2][3]);
      acc[3][0] = fmaf(a4.w, b4.x, acc[3][0]);
      acc[3][1] = fmaf(a4.w, b4.y, acc[3][1]);
      acc[3][2] = fmaf(a4.w, b4.z, acc[3][2]);
      acc[3][3] = fmaf(a4.w, b4.w, acc[3][3]);
    }
    __syncthreads();
  }
#pragma unroll
  for (int r = 0; r < 4; ++r) {
    const int row = rowBase + (ty << 2) + r;
    const float bsv = bias[row];
    float4 o;
    o.x = acc[r][0] + bsv;
    o.y = acc[r][1] + bsv;
    o.z = acc[r][2] + bsv;
    o.w = acc[r][3] + bsv;
    if (RELU) {
      o.x = fmaxf(o.x, 0.f);
      o.y = fmaxf(o.y, 0.f);
      o.z = fmaxf(o.z, 0.f);
      o.w = fmaxf(o.w, 0.f);
    }
    *(float4*)&Cout[row * BNT + colBase + (tx << 2)] = o;
  }
}

// ---------------- Sinkhorn (log domain, 3 iters, dustbin row) ----------------
__global__ __launch_bounds__(256) void sinkhorn_kernel(
    const float* __restrict__ S, const float* __restrict__ dustp,
    float* __restrict__ P) {
  const int b = blockIdx.x, tid = threadIdx.x;
  const int lane = tid & 63, wave = tid >> 6;
  __shared__ float Ms[65][256];
  __shared__ float u[65];
  __shared__ float v[256];
  const float dust = dustp[0];
  for (int idx = tid; idx < 16384; idx += 256) {
    const int m = idx >> 8, n = idx & 255;
    Ms[m][n] = S[m * BNT + b * 256 + n];
  }
  Ms[64][tid] = dust;
  v[tid] = 0.f;
  if (tid < 65) u[tid] = 0.f;
  const float norm = -logf(320.f);
  const float la_dust = norm + logf(192.f);
  __syncthreads();
  for (int it = 0; it < 3; ++it) {
    for (int i = wave; i < 65; i += 4) {
      const float x0 = Ms[i][lane] + v[lane];
      const float x1 = Ms[i][lane + 64] + v[lane + 64];
      const float x2 = Ms[i][lane + 128] + v[lane + 128];
      const float x3 = Ms[i][lane + 192] + v[lane + 192];
      float mm = fmaxf(fmaxf(x0, x1), fmaxf(x2, x3));
#pragma unroll
      for (int off = 32; off; off >>= 1) mm = fmaxf(mm, __shfl_xor(mm, off));
      float s = expf(x0 - mm) + expf(x1 - mm) + expf(x2 - mm) + expf(x3 - mm);
#pragma unroll
      for (int off = 32; off; off >>= 1) s += __shfl_xor(s, off);
      if (lane == 0) u[i] = (i == 64 ? la_dust : norm) - (logf(s) + mm);
    }
    __syncthreads();
    {
      const int n = tid;
      float mm = -1e30f;
      for (int i = 0; i < 65; ++i) mm = fmaxf(mm, Ms[i][n] + u[i]);
      float s = 0.f;
      for (int i = 0; i < 65; ++i) s += expf(Ms[i][n] + u[i] - mm);
      v[n] = norm - (logf(s) + mm);
    }
    __syncthreads();
  }
  for (int idx = tid; idx < 16384; idx += 256) {
    const int m = idx >> 8, n = idx & 255;
    P[b * 16384 + idx] = expf(Ms[m][n] + u[m] + v[n] - norm);
  }
}

// ---------------- VLAD ------------------------------------------------------
__device__ __forceinline__ int ps_idx(int m, int n) {
  return m * 256 + ((((n >> 2) ^ (m & 7)) << 2) | (n & 3));
}
__global__ __launch_bounds__(256) void vlad_kernel(const float* __restrict__ F,
                                                   const float* __restrict__ P,
                                                   float* __restrict__ VL) {
  const int b = blockIdx.x, half = blockIdx.y;
  const int tid = threadIdx.x;
  const int m = tid & 63, lg = tid >> 6;
  __shared__ float ps[64 * 256];
  for (int idx = tid; idx < 16384; idx += 256) {
    const int mm = idx >> 8, n = idx & 255;
    ps[ps_idx(mm, n)] = P[b * 16384 + idx];
  }
  __syncthreads();
  float acc[16];
#pragma unroll
  for (int i = 0; i < 16; ++i) acc[i] = 0.f;
  for (int i = 0; i < 16; ++i) {
    const int ll = half * 64 + lg + 4 * i;
    const float* frow = &F[(size_t)ll * BNT + b * 256];
    float a = 0.f;
#pragma unroll 8
    for (int nq = 0; nq < 64; ++nq) {
      const float4 f4 = *(const float4*)&frow[nq << 2];
      const float4 p4 = *(const float4*)&ps[m * 256 + ((nq ^ (m & 7)) << 2)];
      a = fmaf(f4.x, p4.x, a);
      a = fmaf(f4.y, p4.y, a);
      a = fmaf(f4.z, p4.z, a);
      a = fmaf(f4.w, p4.w, a);
    }
    acc[i] = a;
  }
#pragma unroll
  for (int i = 0; i < 16; ++i) {
    const int ll = half * 64 + lg + 4 * i;
    VL[b * 8192 + ll * 64 + m] = acc[i];
  }
}

// ---------------- finalize ---------------------------------------------------
__global__ __launch_bounds__(256) void finalize_kernel(
    const float* __restrict__ TK, const float* __restrict__ VL,
    float* __restrict__ out) {
  const int b = blockIdx.x, tid = threadIdx.x;
  const int lane = tid & 63, wave = tid >> 6;
  __shared__ float sred[4];
  __shared__ float ssm_part[4][64];
  __shared__ float invm_s[64];
  __shared__ float totals[1];
  const float* vl = &VL[b * 8192];
  float accv = 0.f;
  for (int k = 0; k < 32; ++k) {
    const float xv = vl[tid + 256 * k];
    accv = fmaf(xv, xv, accv);
  }
  ssm_part[wave][lane] = accv;
  const float tv = TK[b * 256 + tid];
  float ss = tv * tv;
#pragma unroll
  for (int off = 32; off; off >>= 1) ss += __shfl_down(ss, off);
  if (lane == 0) sred[wave] = ss;
  __syncthreads();
  const float sstok = sred[0] + sred[1] + sred[2] + sred[3];
  const float invtok = 1.f / fmaxf(sqrtf(sstok), 1e-12f);
  float tpart = 0.f;
  if (wave == 0) {
    const float s4 = ssm_part[0][tid] + ssm_part[1][tid] + ssm_part[2][tid] +
                     ssm_part[3][tid];
    const float inv = 1.f / fmaxf(sqrtf(s4), 1e-12f);
    invm_s[tid] = inv;
    tpart = s4 * inv * inv;
#pragma unroll
    for (int off = 32; off; off >>= 1) tpart += __shfl_down(tpart, off);
    if (lane == 0) totals[0] = tpart;
  }
  __syncthreads();
  const float total = totals[0] + sstok * invtok * invtok;
  const float invT = 1.f / fmaxf(sqrtf(total), 1e-12f);
  float* ob = &out[b * 8448];
  ob[tid] = tv * invtok * invT;
  for (int k = 0; k < 32; ++k) {
    const int idx = tid + 256 * k;
    ob[256 + idx] = vl[idx] * invm_s[idx & 63] * invT;
  }
}

extern "C" void kernel_launch(void* const* d_in, const int* in_sizes, int n_in,
                              void* d_out, int out_size, void* d_ws,
                              size_t ws_size, hipStream_t stream) {
  const float* x = (const float*)d_in[0];
  const float* t = (const float*)d_in[1];
  const float* Wt1 = (const float*)d_in[2];
  const float* bt1 = (const float*)d_in[3];
  const float* Wt2 = (const float*)d_in[4];
  const float* bt2 = (const float*)d_in[5];
  const float* Wc1 = (const float*)d_in[6];
  const float* bc1 = (const float*)d_in[7];
  const float* Wc2 = (const float*)d_in[8];
  const float* bc2 = (const float*)d_in[9];
  const float* Ws1 = (const float*)d_in[10];
  const float* bs1 = (const float*)d_in[11];
  const float* Ws2 = (const float*)d_in[12];
  const float* bs2 = (const float*)d_in[13];
  const float* dust = (const float*)d_in[14];
  float* out = (float*)d_out;

  if (ws_size >= 97714176ull) {
    // Byte layout (97.19 MB total; all overlays are stream-ordered safe):
    // [0, 50331648)           XT bf16 16384x1536 (dead after gemm1 x2)
    //   overlay: P [0,4194304), VL [4194304,6291456)
    // [50331648, 83886080)    HT bf16 16384x1024 (dead after gemm2)
    // [83886080, 96468992)    C2 f32 192xBNT (written by gemm2)
    //   overlay before gemm2: Wc1b @83886080, Ws1b @85458944 (dead after gemm1)
    // [96468992, 96993280)    A2 bf16 256x1024
    // [96993280, 96994304)    b2 f32 256
    // [96994304, 97059840)    TK f32 64x256
    // [97059840, 97190912)    Hh f32 64x512
    char* base = (char*)d_ws;
    ushort* XT = (ushort*)base;
    float* P = (float*)base;
    float* VL = (float*)(base + 4194304);
    ushort* HT = (ushort*)(base + 50331648);
    float* C2 = (float*)(base + 83886080);
    ushort* Wc1b = (ushort*)(base + 83886080);
    ushort* Ws1b = (ushort*)(base + 85458944);
    ushort* A2 = (ushort*)(base + 96468992);
    float* b2 = (float*)(base + 96993280);
    float* TK = (float*)(base + 96994304);
    float* Hh = (float*)(base + 97059840);
    float* F = C2;                         // rows 0..127
    float* Sb = C2 + (size_t)128 * BNT;    // rows 128..191

    gemm_tt<true><<<dim3(8, 1), 256, 0, stream>>>(t, Wt1, bt1, Hh, 1536, 512);
    gemm_tt<false><<<dim3(4, 1), 256, 0, stream>>>(Hh, Wt2, bt2, TK, 512, 256);
    convert_w_bf16<<<768, 256, 0, stream>>>(Wc1, Wc1b, 196608);
    convert_w_bf16<<<768, 256, 0, stream>>>(Ws1, Ws1b, 196608);
    transpose_x_bf16<<<dim3(24, 64), 256, 0, stream>>>(x, XT);
    gemm1_mfma<<<dim3(128, 4), 256, 0, stream>>>(Wc1b, XT, bc1, HT, 0);
    gemm1_mfma<<<dim3(128, 4), 256, 0, stream>>>(Ws1b, XT, bs1, HT, 512);
    build_A2<<<256, 256, 0, stream>>>(Wc2, Ws2, bc2, bs2, A2, b2);
    gemm2_mfma<<<dim3(128, 2), 256, 0, stream>>>(A2, HT, b2, C2);
    sinkhorn_kernel<<<64, 256, 0, stream>>>(Sb, dust, P);
    vlad_kernel<<<dim3(64, 2), 256, 0, stream>>>(F, P, VL);
    finalize_kernel<<<64, 256, 0, stream>>>(TK, VL, out);
  } else {
    // fp32 fallback (fits 52.6 MB)
    float* ws = (float*)d_ws;
    float* H = ws;
    float* F = H + 512 * BNT;
    float* Sb = F + 128 * BNT;
    float* P = Sb + 64 * BNT;
    float* VL = P + 64 * BNT;
    float* TK = VL + 64 * 8192;
    float* Hh = P;  // token done before sinkhorn writes P

    gemm_tt<true><<<dim3(8, 1), 256, 0, stream>>>(t, Wt1, bt1, Hh, 1536, 512);
    gemm_tt<false><<<dim3(4, 1), 256, 0, stream>>>(Hh, Wt2, bt2, TK, 512, 256);
    gemm_tile<true, true><<<dim3(256, 8), 256, 0, stream>>>(Wc1, x, bc1, H, 1536);
    gemm_tile<false, false><<<dim3(256, 2), 256, 0, stream>>>(Wc2, H, bc2, F, 512);
    gemm_tile<true, true><<<dim3(256, 8), 256, 0, stream>>>(Ws1, x, bs1, H, 1536);
    gemm_tile<false, false><<<dim3(256, 1), 256, 0, stream>>>(Ws2, H, bs2, Sb, 512);
    sinkhorn_kernel<<<64, 256, 0, stream>>>(Sb, dust, P);
    vlad_kernel<<<dim3(64, 2), 256, 0, stream>>>(F, P, VL);
    finalize_kernel<<<64, 256, 0, stream>>>(TK, VL, out);
  }
}

// Round 5
// 292.604 us; speedup vs baseline: 5.9025x; 1.2021x over previous
//
#include <hip/hip_runtime.h>
#include <math.h>

// SALAD head. B=64, C=1536, N=256, HID=512, L=128, M=64, G=256. BNT = B*N.
#define BNT 16384

using f32x4 = __attribute__((ext_vector_type(4))) float;
using s16x8 = __attribute__((ext_vector_type(8))) short;

__device__ __forceinline__ unsigned short f32_to_bf16_rne(float f) {
  unsigned int u = __float_as_uint(f);
  u += 0x7FFFu + ((u >> 16) & 1u);
  return (unsigned short)(u >> 16);
}
__device__ __forceinline__ unsigned pack_bf16x2(float a, float b) {
  return (unsigned)f32_to_bf16_rne(a) | ((unsigned)f32_to_bf16_rne(b) << 16);
}

__device__ __forceinline__ void gload_lds16(const ushort* g, ushort* lds) {
  __builtin_amdgcn_global_load_lds(
      (const __attribute__((address_space(1))) unsigned int*)g,
      (__attribute__((address_space(3))) unsigned int*)lds, 16, 0, 0);
}

// ---------------- fp32 -> bf16 convert (vectorized) -------------------------
__global__ __launch_bounds__(256) void convert_w_bf16(
    const float* __restrict__ W, ushort* __restrict__ Wb, int n4) {
  const int i = blockIdx.x * 256 + threadIdx.x;
  if (i < n4) {
    const float4 v = ((const float4*)W)[i];
    uint2 o;
    o.x = pack_bf16x2(v.x, v.y);
    o.y = pack_bf16x2(v.z, v.w);
    ((uint2*)Wb)[i] = o;
  }
}

// ---- token layer 1 (MFMA, no LDS, split-K): Pt[kc] = t-chunk @ Wt1^T -------
// Tb [64][1536] bf16, Wt1b [512][1536] bf16. grid (8 col-tiles, 4 k-chunks).
__global__ __launch_bounds__(256) void token1_mfma(
    const ushort* __restrict__ Tb, const ushort* __restrict__ Wt1b,
    float* __restrict__ Pt) {
  const int ct = blockIdx.x, kc = blockIdx.y;
  const int tid = threadIdx.x, l = tid & 63, wv = tid >> 6;
  const int lr = l & 15, ko = l >> 4;
  const int col = ct * 64 + wv * 16 + lr;  // output unit h
  f32x4 acc[4];
#pragma unroll
  for (int r = 0; r < 4; ++r) acc[r] = (f32x4){0.f, 0.f, 0.f, 0.f};
  const int k0 = kc * 384;
#pragma unroll 4
  for (int ks = 0; ks < 12; ++ks) {
    const int k = k0 + ks * 32 + ko * 8;
    const s16x8 bf = *(const s16x8*)(Wt1b + (size_t)col * 1536 + k);
#pragma unroll
    for (int rf = 0; rf < 4; ++rf) {
      const s16x8 af = *(const s16x8*)(Tb + (size_t)(rf * 16 + lr) * 1536 + k);
      acc[rf] =
          __builtin_amdgcn_mfma_f32_16x16x32_bf16(af, bf, acc[rf], 0, 0, 0);
    }
  }
#pragma unroll
  for (int rf = 0; rf < 4; ++rf)
#pragma unroll
    for (int j = 0; j < 4; ++j) {
      const int row = rf * 16 + ko * 4 + j;  // batch b
      Pt[((kc * 64 + row) << 9) + col] = acc[rf][j];
    }
}

// ---- token layer-1 reduce: Hb[64][512] bf16 = relu(sum_kc Pt + bt1) --------
__global__ __launch_bounds__(256) void token1_reduce(
    const float* __restrict__ Pt, const float* __restrict__ bt1,
    ushort* __restrict__ Hb) {
  const int i = blockIdx.x * 256 + threadIdx.x;  // 16384 pairs
  const int row = i >> 8, c2 = (i & 255) * 2;
  float v0 = bt1[c2], v1 = bt1[c2 + 1];
#pragma unroll
  for (int kc = 0; kc < 4; ++kc) {
    v0 += Pt[((kc * 64 + row) << 9) + c2];
    v1 += Pt[((kc * 64 + row) << 9) + c2 + 1];
  }
  v0 = fmaxf(v0, 0.f);
  v1 = fmaxf(v1, 0.f);
  ((unsigned*)Hb)[i] = pack_bf16x2(v0, v1);
}

// ---- token layer 2 (MFMA, no LDS): TK[64][256] f32 = Hb @ Wt2^T + bt2 ------
__global__ __launch_bounds__(256) void token2_mfma(
    const ushort* __restrict__ Hb, const ushort* __restrict__ Wt2b,
    const float* __restrict__ bt2, float* __restrict__ TK) {
  const int ct = blockIdx.x;  // 4
  const int tid = threadIdx.x, l = tid & 63, wv = tid >> 6;
  const int lr = l & 15, ko = l >> 4;
  const int col = ct * 64 + wv * 16 + lr;  // output g
  f32x4 acc[4];
#pragma unroll
  for (int r = 0; r < 4; ++r) acc[r] = (f32x4){0.f, 0.f, 0.f, 0.f};
#pragma unroll 4
  for (int ks = 0; ks < 16; ++ks) {
    const int k = ks * 32 + ko * 8;
    const s16x8 bf = *(const s16x8*)(Wt2b + (size_t)col * 512 + k);
#pragma unroll
    for (int rf = 0; rf < 4; ++rf) {
      const s16x8 af = *(const s16x8*)(Hb + (size_t)(rf * 16 + lr) * 512 + k);
      acc[rf] =
          __builtin_amdgcn_mfma_f32_16x16x32_bf16(af, bf, acc[rf], 0, 0, 0);
    }
  }
  const float bb = bt2[col];
#pragma unroll
  for (int rf = 0; rf < 4; ++rf)
#pragma unroll
    for (int j = 0; j < 4; ++j)
      TK[(rf * 16 + ko * 4 + j) * 256 + col] = acc[rf][j] + bb;
}

// ---- stacked bias b1[1024] = [bc1; bs1] ------------------------------------
__global__ __launch_bounds__(256) void build_b1(const float* __restrict__ bc1,
                                                const float* __restrict__ bs1,
                                                float* __restrict__ b1) {
  const int i = blockIdx.x * 256 + threadIdx.x;
  b1[i] = i < 512 ? bc1[i] : bs1[i - 512];
}

// ------- x [64][1536][256] fp32 -> XT [16384][1536] bf16 (transpose) --------
__global__ __launch_bounds__(256) void transpose_x_bf16(
    const float* __restrict__ x, ushort* __restrict__ XT) {
  const int cc = blockIdx.x * 64;
  const int b = blockIdx.y;
  const int n = threadIdx.x;
  const float* src = x + b * 393216 + cc * 256 + n;
  ushort* dst = XT + (b * 256 + n) * 1536 + cc;
#pragma unroll
  for (int g = 0; g < 8; ++g) {
    float v[8];
#pragma unroll
    for (int j = 0; j < 8; ++j) v[j] = src[(g * 8 + j) * 256];
    uint4 o;
    o.x = pack_bf16x2(v[0], v[1]);
    o.y = pack_bf16x2(v[2], v[3]);
    o.z = pack_bf16x2(v[4], v[5]);
    o.w = pack_bf16x2(v[6], v[7]);
    *(uint4*)(dst + g * 8) = o;
  }
}

// ---- layer-1 MFMA GEMM (fused cluster+score): -------------------------------
// HT[j][h] = bf16(relu(A1[h]·XT[j] + b1[h])), A1 [1024][1536] stacked.
// grid (8 m-tiles, 128 n-tiles) — m-inner linear order => XT panel L2 reuse.
__global__ __launch_bounds__(256) void gemm1_mfma(
    const ushort* __restrict__ A1, const ushort* __restrict__ Bt,
    const float* __restrict__ b1, ushort* __restrict__ HT) {
  constexpr int K = 1536;
  __shared__ ushort As[128 * 32];
  __shared__ ushort Bs[128 * 32];
  const int tid = threadIdx.x;
  const int l = tid & 63, w = tid >> 6;
  const int m0 = blockIdx.x * 128, n0 = blockIdx.y * 128;
  const int wr = w >> 1, wc = w & 1;
  const int lr = l & 15, kq = l >> 4;

  f32x4 acc[4][4];
#pragma unroll
  for (int mi = 0; mi < 4; ++mi)
#pragma unroll
    for (int ni = 0; ni < 4; ++ni) acc[mi][ni] = (f32x4){0.f, 0.f, 0.f, 0.f};

  const int rA0 = tid >> 2;
  const int q8 = (tid & 3) * 8;
  ushort* AsW0 = As + (w * 64) * 8;
  ushort* AsW1 = As + (256 + w * 64) * 8;
  ushort* BsW0 = Bs + (w * 64) * 8;
  ushort* BsW1 = Bs + (256 + w * 64) * 8;
  const ushort* Arow0 = A1 + (size_t)(m0 + rA0) * K + q8;
  const ushort* Arow1 = A1 + (size_t)(m0 + rA0 + 64) * K + q8;
  const ushort* Brow0 = Bt + (size_t)(n0 + rA0) * K + q8;
  const ushort* Brow1 = Bt + (size_t)(n0 + rA0 + 64) * K + q8;

  for (int k0 = 0; k0 < K; k0 += 32) {
    __syncthreads();
    gload_lds16(Arow0 + k0, AsW0);
    gload_lds16(Arow1 + k0, AsW1);
    gload_lds16(Brow0 + k0, BsW0);
    gload_lds16(Brow1 + k0, BsW1);
    __syncthreads();
    s16x8 af[4], bfr[4];
#pragma unroll
    for (int mi = 0; mi < 4; ++mi)
      af[mi] = *(const s16x8*)(As + (wr * 64 + mi * 16 + lr) * 32 + kq * 8);
#pragma unroll
    for (int ni = 0; ni < 4; ++ni)
      bfr[ni] = *(const s16x8*)(Bs + (wc * 64 + ni * 16 + lr) * 32 + kq * 8);
#pragma unroll
    for (int mi = 0; mi < 4; ++mi)
#pragma unroll
      for (int ni = 0; ni < 4; ++ni)
        acc[mi][ni] = __builtin_amdgcn_mfma_f32_16x16x32_bf16(
            af[mi], bfr[ni], acc[mi][ni], 0, 0, 0);
  }

  // h = m0+wr*64+mi*16+kq*4+j, token col = n0+wc*64+ni*16+lr.
#pragma unroll
  for (int mi = 0; mi < 4; ++mi) {
    const int rbase = m0 + wr * 64 + mi * 16 + kq * 4;
    float b4[4];
#pragma unroll
    for (int j = 0; j < 4; ++j) b4[j] = b1[rbase + j];
#pragma unroll
    for (int ni = 0; ni < 4; ++ni) {
      const int col = n0 + wc * 64 + ni * 16 + lr;
      const float v0 = fmaxf(acc[mi][ni][0] + b4[0], 0.f);
      const float v1 = fmaxf(acc[mi][ni][1] + b4[1], 0.f);
      const float v2 = fmaxf(acc[mi][ni][2] + b4[2], 0.f);
      const float v3 = fmaxf(acc[mi][ni][3] + b4[3], 0.f);
      uint2 o;
      o.x = pack_bf16x2(v0, v1);
      o.y = pack_bf16x2(v2, v3);
      *(uint2*)(HT + (size_t)col * 1024 + rbase) = o;
    }
  }
}

// ---- layer-2 MFMA GEMM: C2[192][BNT] = A2[256][1024] @ HT^T + b2 -----------
// grid (2 m-tiles, 128 n-tiles) — m-inner for HT panel reuse.
__global__ __launch_bounds__(256) void gemm2_mfma(
    const ushort* __restrict__ A2, const ushort* __restrict__ HT,
    const float* __restrict__ b2, float* __restrict__ C2) {
  constexpr int K = 1024;
  __shared__ ushort As[128 * 32];
  __shared__ ushort Bs[128 * 32];
  const int tid = threadIdx.x;
  const int l = tid & 63, w = tid >> 6;
  const int m0 = blockIdx.x * 128, n0 = blockIdx.y * 128;
  const int wr = w >> 1, wc = w & 1;
  const int lr = l & 15, kq = l >> 4;

  f32x4 acc[4][4];
#pragma unroll
  for (int mi = 0; mi < 4; ++mi)
#pragma unroll
    for (int ni = 0; ni < 4; ++ni) acc[mi][ni] = (f32x4){0.f, 0.f, 0.f, 0.f};

  const int rA0 = tid >> 2;
  const int q8 = (tid & 3) * 8;
  ushort* AsW0 = As + (w * 64) * 8;
  ushort* AsW1 = As + (256 + w * 64) * 8;
  ushort* BsW0 = Bs + (w * 64) * 8;
  ushort* BsW1 = Bs + (256 + w * 64) * 8;
  const ushort* Arow0 = A2 + (size_t)(m0 + rA0) * K + q8;
  const ushort* Arow1 = A2 + (size_t)(m0 + rA0 + 64) * K + q8;
  const ushort* Brow0 = HT + (size_t)(n0 + rA0) * K + q8;
  const ushort* Brow1 = HT + (size_t)(n0 + rA0 + 64) * K + q8;

  for (int k0 = 0; k0 < K; k0 += 32) {
    __syncthreads();
    gload_lds16(Arow0 + k0, AsW0);
    gload_lds16(Arow1 + k0, AsW1);
    gload_lds16(Brow0 + k0, BsW0);
    gload_lds16(Brow1 + k0, BsW1);
    __syncthreads();
    s16x8 af[4], bfr[4];
#pragma unroll
    for (int mi = 0; mi < 4; ++mi)
      af[mi] = *(const s16x8*)(As + (wr * 64 + mi * 16 + lr) * 32 + kq * 8);
#pragma unroll
    for (int ni = 0; ni < 4; ++ni)
      bfr[ni] = *(const s16x8*)(Bs + (wc * 64 + ni * 16 + lr) * 32 + kq * 8);
#pragma unroll
    for (int mi = 0; mi < 4; ++mi)
#pragma unroll
      for (int ni = 0; ni < 4; ++ni)
        acc[mi][ni] = __builtin_amdgcn_mfma_f32_16x16x32_bf16(
            af[mi], bfr[ni], acc[mi][ni], 0, 0, 0);
  }

#pragma unroll
  for (int mi = 0; mi < 4; ++mi) {
    const int rbase = m0 + wr * 64 + mi * 16 + kq * 4;
    if (rbase < 192) {
      float b4[4];
#pragma unroll
      for (int j = 0; j < 4; ++j) b4[j] = b2[rbase + j];
#pragma unroll
      for (int ni = 0; ni < 4; ++ni) {
        const int col = n0 + wc * 64 + ni * 16 + lr;
        float* cr = C2 + (size_t)rbase * BNT + col;
#pragma unroll
        for (int j = 0; j < 4; ++j) cr[(size_t)j * BNT] = acc[mi][ni][j] + b4[j];
      }
    }
  }
}

// ---- build stacked layer-2 weights: A2[256][1024] bf16, b2[256] ------------
__global__ __launch_bounds__(256) void build_A2(
    const float* __restrict__ Wc2, const float* __restrict__ Ws2,
    const float* __restrict__ bc2, const float* __restrict__ bs2,
    ushort* __restrict__ A2, float* __restrict__ b2) {
  const int r = blockIdx.x;
  const int c = threadIdx.x * 4;
  float v[4] = {0.f, 0.f, 0.f, 0.f};
  if (r < 128) {
    if (c < 512) {
#pragma unroll
      for (int j = 0; j < 4; ++j) v[j] = Wc2[r * 512 + c + j];
    }
  } else if (r < 192) {
    if (c >= 512) {
#pragma unroll
      for (int j = 0; j < 4; ++j) v[j] = Ws2[(r - 128) * 512 + (c - 512) + j];
    }
  }
  uint2 o;
  o.x = pack_bf16x2(v[0], v[1]);
  o.y = pack_bf16x2(v[2], v[3]);
  *(uint2*)(A2 + r * 1024 + c) = o;
  if (threadIdx.x == 0)
    b2[r] = r < 128 ? bc2[r] : (r < 192 ? bs2[r - 128] : 0.f);
}

// ---------------- fp32 GEMMs (fallback path only) ---------------------------
template <bool RELU>
__global__ __launch_bounds__(256) void gemm_tt(
    const float* __restrict__ A, const float* __restrict__ Bw,
    const float* __restrict__ bias, float* __restrict__ C, int K, int Nn) {
  __shared__ float As[16][68];
  __shared__ float Bs[16][68];
  const int tid = threadIdx.x;
  const int tx = tid & 15, ty = tid >> 4;
  const int n0 = blockIdx.x * 64;
  const int lrow = tid >> 2, lkq = (tid & 3) << 2;
  float acc[4][4];
#pragma unroll
  for (int r = 0; r < 4; ++r)
#pragma unroll
    for (int c = 0; c < 4; ++c) acc[r][c] = 0.f;
  for (int k0 = 0; k0 < K; k0 += 16) {
    const float4 av = *(const float4*)&A[lrow * K + k0 + lkq];
    const float4 bv = *(const float4*)&Bw[(n0 + lrow) * K + k0 + lkq];
    As[lkq + 0][lrow] = av.x;
    As[lkq + 1][lrow] = av.y;
    As[lkq + 2][lrow] = av.z;
    As[lkq + 3][lrow] = av.w;
    Bs[lkq + 0][lrow] = bv.x;
    Bs[lkq + 1][lrow] = bv.y;
    Bs[lkq + 2][lrow] = bv.z;
    Bs[lkq + 3][lrow] = bv.w;
    __syncthreads();
#pragma unroll
    for (int kk = 0; kk < 16; ++kk) {
      const float4 a4 = *(const float4*)&As[kk][ty << 2];
      const float4 b4 = *(const float4*)&Bs[kk][tx << 2];
      acc[0][0] = fmaf(a4.x, b4.x, acc[0][0]);
      acc[0][1] = fmaf(a4.x, b4.y, acc[0][1]);
      acc[0][2] = fmaf(a4.x, b4.z, acc[0][2]);
      acc[0][3] = fmaf(a4.x, b4.w, acc[0][3]);
      acc[1][0] = fmaf(a4.y, b4.x, acc[1][0]);
      acc[1][1] = fmaf(a4.y, b4.y, acc[1][1]);
      acc[1][2] = fmaf(a4.y, b4.z, acc[1][2]);
      acc[1][3] = fmaf(a4.y, b4.w, acc[1][3]);
      acc[2][0] = fmaf(a4.z, b4.x, acc[2][0]);
      acc[2][1] = fmaf(a4.z, b4.y, acc[2][1]);
      acc[2][2] = fmaf(a4.z, b4.z, acc[2][2]);
      acc[2][3] = fmaf(a4.z, b4.w, acc[2][3]);
      acc[3][0] = fmaf(a4.w, b4.x, acc[3][0]);
      acc[3][1] = fmaf(a4.w, b4.y, acc[3][1]);
      acc[3][2] = fmaf(a4.w, b4.z, acc[3][2]);
      acc[3][3] = fmaf(a4.w, b4.w, acc[3][3]);
    }
    __syncthreads();
  }
#pragma unroll
  for (int r = 0; r < 4; ++r) {
    const int row = (ty << 2) + r;
    float4 o;
    o.x = acc[r][0] + bias[n0 + (tx << 2) + 0];
    o.y = acc[r][1] + bias[n0 + (tx << 2) + 1];
    o.z = acc[r][2] + bias[n0 + (tx << 2) + 2];
    o.w = acc[r][3] + bias[n0 + (tx << 2) + 3];
    if (RELU) {
      o.x = fmaxf(o.x, 0.f);
      o.y = fmaxf(o.y, 0.f);
      o.z = fmaxf(o.z, 0.f);
      o.w = fmaxf(o.w, 0.f);
    }
    *(float4*)&C[row * Nn + n0 + (tx << 2)] = o;
  }
}

template <bool XVIEW, bool RELU>
__global__ __launch_bounds__(256) void gemm_tile(
    const float* __restrict__ A, const float* __restrict__ Bsrc,
    const float* __restrict__ bias, float* __restrict__ Cout, int K) {
  __shared__ float As[16][68];
  __shared__ float Bsh[16][68];
  const int tid = threadIdx.x;
  const int tx = tid & 15, ty = tid >> 4;
  const int rowBase = blockIdx.y * 64;
  const int colBase = blockIdx.x * 64;
  const int bb = colBase >> 8, n0 = colBase & 255;
  const int boff = XVIEW ? (bb * 393216 + n0) : colBase;
  const int la_row = tid >> 2, la_kq = (tid & 3) << 2;
  const int lb_k = tid >> 4, lb_c = (tid & 15) << 2;
  float acc[4][4];
#pragma unroll
  for (int r = 0; r < 4; ++r)
#pragma unroll
    for (int c = 0; c < 4; ++c) acc[r][c] = 0.f;
  for (int k0 = 0; k0 < K; k0 += 16) {
    const float4 av = *(const float4*)&A[(rowBase + la_row) * K + k0 + la_kq];
    float4 bv;
    if (XVIEW)
      bv = *(const float4*)&Bsrc[boff + (k0 + lb_k) * 256 + lb_c];
    else
      bv = *(const float4*)&Bsrc[(k0 + lb_k) * BNT + boff + lb_c];
    As[la_kq + 0][la_row] = av.x;
    As[la_kq + 1][la_row] = av.y;
    As[la_kq + 2][la_row] = av.z;
    As[la_kq + 3][la_row] = av.w;
    *(float4*)&Bsh[lb_k][lb_c] = bv;
    __syncthreads();
#pragma unroll
    for (int kk = 0; kk < 16; ++kk) {
      const float4 a4 = *(const float4*)&As[kk][ty << 2];
      const float4 b4 = *(const float4*)&Bsh[kk][tx << 2];
      acc[0][0] = fmaf(a4.x, b4.x, acc[0][0]);
      acc[0][1] = fmaf(a4.x, b4.y, acc[0][1]);
      acc[0][2] = fmaf(a4.x, b4.z, acc[0][2]);
      acc[0][3] = fmaf(a4.x, b4.w, acc[0][3]);
      acc[1][0] = fmaf(a4.y, b4.x, acc[1][0]);
      acc[1][1] = fmaf(a4.y, b4.y, acc[1][1]);
      acc[1][2] = fmaf(a4.y, b4.z, acc[1][2]);
      acc[1][3] = fmaf(a4.y, b4.w, acc[1][3]);
      acc[2][0] = fmaf(a4.z, b4.x, acc[2][0]);
      acc[2][1] = fmaf(a4.z, b4.y, acc[2][1]);
      acc[2][2] = fmaf(a4.z, b4.z, acc[2][2]);
      acc[2][3] = fmaf(a4.z, b4.w, acc[2][3]);
      acc[3][0] = fmaf(a4.w, b4.x, acc[3][0]);
      acc[3][1] = fmaf(a4.w, b4.y, acc[3][1]);
      acc[3][2] = fmaf(a4.w, b4.z, acc[3][2]);
      acc[3][3] = fmaf(a4.w, b4.w, acc[3][3]);
    }
    __syncthreads();
  }
#pragma unroll
  for (int r = 0; r < 4; ++r) {
    const int row = rowBase + (ty << 2) + r;
    const float bsv = bias[row];
    float4 o;
    o.x = acc[r][0] + bsv;
    o.y = acc[r][1] + bsv;
    o.z = acc[r][2] + bsv;
    o.w = acc[r][3] + bsv;
    if (RELU) {
      o.x = fmaxf(o.x, 0.f);
      o.y = fmaxf(o.y, 0.f);
      o.z = fmaxf(o.z, 0.f);
      o.w = fmaxf(o.w, 0.f);
    }
    *(float4*)&Cout[row * BNT + colBase + (tx << 2)] = o;
  }
}

// ---------------- Sinkhorn (log domain, 3 iters, dustbin row) ----------------
__global__ __launch_bounds__(256) void sinkhorn_kernel(
    const float* __restrict__ S, const float* __restrict__ dustp,
    float* __restrict__ P) {
  const int b = blockIdx.x, tid = threadIdx.x;
  const int lane = tid & 63, wave = tid >> 6;
  __shared__ float Ms[65][256];
  __shared__ float u[65];
  __shared__ float v[256];
  const float dust = dustp[0];
  for (int idx = tid; idx < 16384; idx += 256) {
    const int m = idx >> 8, n = idx & 255;
    Ms[m][n] = S[m * BNT + b * 256 + n];
  }
  Ms[64][tid] = dust;
  v[tid] = 0.f;
  if (tid < 65) u[tid] = 0.f;
  const float norm = -logf(320.f);
  const float la_dust = norm + logf(192.f);
  __syncthreads();
  for (int it = 0; it < 3; ++it) {
    for (int i = wave; i < 65; i += 4) {
      const float x0 = Ms[i][lane] + v[lane];
      const float x1 = Ms[i][lane + 64] + v[lane + 64];
      const float x2 = Ms[i][lane + 128] + v[lane + 128];
      const float x3 = Ms[i][lane + 192] + v[lane + 192];
      float mm = fmaxf(fmaxf(x0, x1), fmaxf(x2, x3));
#pragma unroll
      for (int off = 32; off; off >>= 1) mm = fmaxf(mm, __shfl_xor(mm, off));
      float s = expf(x0 - mm) + expf(x1 - mm) + expf(x2 - mm) + expf(x3 - mm);
#pragma unroll
      for (int off = 32; off; off >>= 1) s += __shfl_xor(s, off);
      if (lane == 0) u[i] = (i == 64 ? la_dust : norm) - (logf(s) + mm);
    }
    __syncthreads();
    {
      const int n = tid;
      float mm = -1e30f;
      for (int i = 0; i < 65; ++i) mm = fmaxf(mm, Ms[i][n] + u[i]);
      float s = 0.f;
      for (int i = 0; i < 65; ++i) s += expf(Ms[i][n] + u[i] - mm);
      v[n] = norm - (logf(s) + mm);
    }
    __syncthreads();
  }
  for (int idx = tid; idx < 16384; idx += 256) {
    const int m = idx >> 8, n = idx & 255;
    P[b * 16384 + idx] = expf(Ms[m][n] + u[m] + v[n] - norm);
  }
}

// ---------------- VLAD ------------------------------------------------------
__device__ __forceinline__ int ps_idx(int m, int n) {
  return m * 256 + ((((n >> 2) ^ (m & 7)) << 2) | (n & 3));
}
__global__ __launch_bounds__(256) void vlad_kernel(const float* __restrict__ F,
                                                   const float* __restrict__ P,
                                                   float* __restrict__ VL) {
  const int b = blockIdx.x, half = blockIdx.y;
  const int tid = threadIdx.x;
  const int m = tid & 63, lg = tid >> 6;
  __shared__ float ps[64 * 256];
  for (int idx = tid; idx < 16384; idx += 256) {
    const int mm = idx >> 8, n = idx & 255;
    ps[ps_idx(mm, n)] = P[b * 16384 + idx];
  }
  __syncthreads();
  float acc[16];
#pragma unroll
  for (int i = 0; i < 16; ++i) acc[i] = 0.f;
  for (int i = 0; i < 16; ++i) {
    const int ll = half * 64 + lg + 4 * i;
    const float* frow = &F[(size_t)ll * BNT + b * 256];
    float a = 0.f;
#pragma unroll 8
    for (int nq = 0; nq < 64; ++nq) {
      const float4 f4 = *(const float4*)&frow[nq << 2];
      const float4 p4 = *(const float4*)&ps[m * 256 + ((nq ^ (m & 7)) << 2)];
      a = fmaf(f4.x, p4.x, a);
      a = fmaf(f4.y, p4.y, a);
      a = fmaf(f4.z, p4.z, a);
      a = fmaf(f4.w, p4.w, a);
    }
    acc[i] = a;
  }
#pragma unroll
  for (int i = 0; i < 16; ++i) {
    const int ll = half * 64 + lg + 4 * i;
    VL[b * 8192 + ll * 64 + m] = acc[i];
  }
}

// ---------------- finalize ---------------------------------------------------
__global__ __launch_bounds__(256) void finalize_kernel(
    const float* __restrict__ TK, const float* __restrict__ VL,
    float* __restrict__ out) {
  const int b = blockIdx.x, tid = threadIdx.x;
  const int lane = tid & 63, wave = tid >> 6;
  __shared__ float sred[4];
  __shared__ float ssm_part[4][64];
  __shared__ float invm_s[64];
  __shared__ float totals[1];
  const float* vl = &VL[b * 8192];
  float accv = 0.f;
  for (int k = 0; k < 32; ++k) {
    const float xv = vl[tid + 256 * k];
    accv = fmaf(xv, xv, accv);
  }
  ssm_part[wave][lane] = accv;
  const float tv = TK[b * 256 + tid];
  float ss = tv * tv;
#pragma unroll
  for (int off = 32; off; off >>= 1) ss += __shfl_down(ss, off);
  if (lane == 0) sred[wave] = ss;
  __syncthreads();
  const float sstok = sred[0] + sred[1] + sred[2] + sred[3];
  const float invtok = 1.f / fmaxf(sqrtf(sstok), 1e-12f);
  float tpart = 0.f;
  if (wave == 0) {
    const float s4 = ssm_part[0][tid] + ssm_part[1][tid] + ssm_part[2][tid] +
                     ssm_part[3][tid];
    const float inv = 1.f / fmaxf(sqrtf(s4), 1e-12f);
    invm_s[tid] = inv;
    tpart = s4 * inv * inv;
#pragma unroll
    for (int off = 32; off; off >>= 1) tpart += __shfl_down(tpart, off);
    if (lane == 0) totals[0] = tpart;
  }
  __syncthreads();
  const float total = totals[0] + sstok * invtok * invtok;
  const float invT = 1.f / fmaxf(sqrtf(total), 1e-12f);
  float* ob = &out[b * 8448];
  ob[tid] = tv * invtok * invT;
  for (int k = 0; k < 32; ++k) {
    const int idx = tid + 256 * k;
    ob[256 + idx] = vl[idx] * invm_s[idx & 63] * invT;
  }
}

extern "C" void kernel_launch(void* const* d_in, const int* in_sizes, int n_in,
                              void* d_out, int out_size, void* d_ws,
                              size_t ws_size, hipStream_t stream) {
  const float* x = (const float*)d_in[0];
  const float* t = (const float*)d_in[1];
  const float* Wt1 = (const float*)d_in[2];
  const float* bt1 = (const float*)d_in[3];
  const float* Wt2 = (const float*)d_in[4];
  const float* bt2 = (const float*)d_in[5];
  const float* Wc1 = (const float*)d_in[6];
  const float* bc1 = (const float*)d_in[7];
  const float* Wc2 = (const float*)d_in[8];
  const float* bc2 = (const float*)d_in[9];
  const float* Ws1 = (const float*)d_in[10];
  const float* bs1 = (const float*)d_in[11];
  const float* Ws2 = (const float*)d_in[12];
  const float* bs2 = (const float*)d_in[13];
  const float* dust = (const float*)d_in[14];
  float* out = (float*)d_out;

  if (ws_size >= 97714176ull) {
    // Byte layout (stream-ordered overlays):
    // [0, 50331648)        XT bf16 16384x1536
    //   pre-transpose overlay (token scratch): Tb@0 (196608), Wt1b@196608
    //     (1572864), Wt2b@1769472 (262144), Pt@2031616 (524288 f32),
    //     Hb@2555904 (65536)
    //   post-gemm1 overlay: P@0 (4194304), VL@4194304 (2097152)
    // [50331648, 83886080) HT bf16 16384x1024
    // [83886080, 96468992) C2 f32 192xBNT; pre-gemm2 overlay: A1 (Wc1b@
    //                      83886080 + Ws1b@85458944, contiguous [1024][1536])
    // [96468992, 96993280) A2 bf16 256x1024
    // [96993280, 96994304) b2 f32 256
    // [96994304, 97059840) TK f32 64x256
    // [97059840, 97063936) b1 f32 1024
    char* base = (char*)d_ws;
    ushort* Tb = (ushort*)base;
    ushort* Wt1b = (ushort*)(base + 196608);
    ushort* Wt2b = (ushort*)(base + 1769472);
    float* Pt = (float*)(base + 2031616);
    ushort* Hb = (ushort*)(base + 2555904);
    ushort* XT = (ushort*)base;
    float* P = (float*)base;
    float* VL = (float*)(base + 4194304);
    ushort* HT = (ushort*)(base + 50331648);
    float* C2 = (float*)(base + 83886080);
    ushort* A1 = (ushort*)(base + 83886080);
    ushort* Wc1b = A1;
    ushort* Ws1b = (ushort*)(base + 85458944);
    ushort* A2 = (ushort*)(base + 96468992);
    float* b2 = (float*)(base + 96993280);
    float* TK = (float*)(base + 96994304);
    float* b1 = (float*)(base + 97059840);
    float* F = C2;                       // rows 0..127
    float* Sb = C2 + (size_t)128 * BNT;  // rows 128..191

    // token path (MFMA, no barriers)
    convert_w_bf16<<<96, 256, 0, stream>>>(t, Tb, 24576);
    convert_w_bf16<<<768, 256, 0, stream>>>(Wt1, Wt1b, 196608);
    convert_w_bf16<<<128, 256, 0, stream>>>(Wt2, Wt2b, 32768);
    token1_mfma<<<dim3(8, 4), 256, 0, stream>>>(Tb, Wt1b, Pt);
    token1_reduce<<<64, 256, 0, stream>>>(Pt, bt1, Hb);
    token2_mfma<<<4, 256, 0, stream>>>(Hb, Wt2b, bt2, TK);
    // main path
    convert_w_bf16<<<768, 256, 0, stream>>>(Wc1, Wc1b, 196608);
    convert_w_bf16<<<768, 256, 0, stream>>>(Ws1, Ws1b, 196608);
    build_b1<<<4, 256, 0, stream>>>(bc1, bs1, b1);
    transpose_x_bf16<<<dim3(24, 64), 256, 0, stream>>>(x, XT);
    gemm1_mfma<<<dim3(8, 128), 256, 0, stream>>>(A1, XT, b1, HT);
    build_A2<<<256, 256, 0, stream>>>(Wc2, Ws2, bc2, bs2, A2, b2);
    gemm2_mfma<<<dim3(2, 128), 256, 0, stream>>>(A2, HT, b2, C2);
    sinkhorn_kernel<<<64, 256, 0, stream>>>(Sb, dust, P);
    vlad_kernel<<<dim3(64, 2), 256, 0, stream>>>(F, P, VL);
    finalize_kernel<<<64, 256, 0, stream>>>(TK, VL, out);
  } else {
    // fp32 fallback (fits 52.6 MB)
    float* ws = (float*)d_ws;
    float* H = ws;
    float* F = H + 512 * BNT;
    float* Sb = F + 128 * BNT;
    float* P = Sb + 64 * BNT;
    float* VL = P + 64 * BNT;
    float* TK = VL + 64 * 8192;
    float* Hh = P;

    gemm_tt<true><<<dim3(8, 1), 256, 0, stream>>>(t, Wt1, bt1, Hh, 1536, 512);
    gemm_tt<false><<<dim3(4, 1), 256, 0, stream>>>(Hh, Wt2, bt2, TK, 512, 256);
    gemm_tile<true, true><<<dim3(256, 8), 256, 0, stream>>>(Wc1, x, bc1, H, 1536);
    gemm_tile<false, false><<<dim3(256, 2), 256, 0, stream>>>(Wc2, H, bc2, F, 512);
    gemm_tile<true, true><<<dim3(256, 8), 256, 0, stream>>>(Ws1, x, bs1, H, 1536);
    gemm_tile<false, false><<<dim3(256, 1), 256, 0, stream>>>(Ws2, H, bs2, Sb, 512);
    sinkhorn_kernel<<<64, 256, 0, stream>>>(Sb, dust, P);
    vlad_kernel<<<dim3(64, 2), 256, 0, stream>>>(F, P, VL);
    finalize_kernel<<<64, 256, 0, stream>>>(TK, VL, out);
  }
}

// Round 6
// 257.424 us; speedup vs baseline: 6.7092x; 1.1367x over previous
//
#include <hip/hip_runtime.h>
#include <math.h>

// SALAD head. B=64, C=1536, N=256, HID=512, L=128, M=64, G=256. BNT = B*N.
#define BNT 16384

using f32x4 = __attribute__((ext_vector_type(4))) float;
using s16x8 = __attribute__((ext_vector_type(8))) short;

__device__ __forceinline__ unsigned short f32_to_bf16_rne(float f) {
  unsigned int u = __float_as_uint(f);
  u += 0x7FFFu + ((u >> 16) & 1u);
  return (unsigned short)(u >> 16);
}
__device__ __forceinline__ unsigned pack_bf16x2(float a, float b) {
  return (unsigned)f32_to_bf16_rne(a) | ((unsigned)f32_to_bf16_rne(b) << 16);
}

__device__ __forceinline__ void gload_lds16(const ushort* g, ushort* lds) {
  __builtin_amdgcn_global_load_lds(
      (const __attribute__((address_space(1))) unsigned int*)g,
      (__attribute__((address_space(3))) unsigned int*)lds, 16, 0, 0);
}

// ---- fused prep: bf16 converts of t,Wt1,Wt2,Wc1,Ws1 + b1 stack + A2 stack --
__global__ __launch_bounds__(256) void prep_all(
    const float* __restrict__ t, const float* __restrict__ Wt1,
    const float* __restrict__ Wt2, const float* __restrict__ Wc1,
    const float* __restrict__ Ws1, const float* __restrict__ bc1,
    const float* __restrict__ bs1, const float* __restrict__ Wc2,
    const float* __restrict__ Ws2, const float* __restrict__ bc2,
    const float* __restrict__ bs2, ushort* __restrict__ Tb,
    ushort* __restrict__ Wt1b, ushort* __restrict__ Wt2b,
    ushort* __restrict__ Wc1b, ushort* __restrict__ Ws1b,
    float* __restrict__ b1, ushort* __restrict__ A2, float* __restrict__ b2) {
  const int bid = blockIdx.x, tid = threadIdx.x;
  const float* src = nullptr;
  ushort* dst = nullptr;
  int i = 0;
  if (bid < 96) {
    src = t; dst = Tb; i = bid * 256 + tid;
  } else if (bid < 864) {
    src = Wt1; dst = Wt1b; i = (bid - 96) * 256 + tid;
  } else if (bid < 992) {
    src = Wt2; dst = Wt2b; i = (bid - 864) * 256 + tid;
  } else if (bid < 1760) {
    src = Wc1; dst = Wc1b; i = (bid - 992) * 256 + tid;
  } else if (bid < 2528) {
    src = Ws1; dst = Ws1b; i = (bid - 1760) * 256 + tid;
  } else if (bid < 2532) {
    const int j = (bid - 2528) * 256 + tid;
    b1[j] = j < 512 ? bc1[j] : bs1[j - 512];
    return;
  } else {
    const int r = bid - 2532;
    const int c = tid * 4;
    float v[4] = {0.f, 0.f, 0.f, 0.f};
    if (r < 128) {
      if (c < 512) {
#pragma unroll
        for (int j = 0; j < 4; ++j) v[j] = Wc2[r * 512 + c + j];
      }
    } else if (r < 192) {
      if (c >= 512) {
#pragma unroll
        for (int j = 0; j < 4; ++j) v[j] = Ws2[(r - 128) * 512 + (c - 512) + j];
      }
    }
    uint2 o;
    o.x = pack_bf16x2(v[0], v[1]);
    o.y = pack_bf16x2(v[2], v[3]);
    *(uint2*)(A2 + r * 1024 + c) = o;
    if (tid == 0) b2[r] = r < 128 ? bc2[r] : (r < 192 ? bs2[r - 128] : 0.f);
    return;
  }
  const float4 v = ((const float4*)src)[i];
  uint2 o;
  o.x = pack_bf16x2(v.x, v.y);
  o.y = pack_bf16x2(v.z, v.w);
  ((uint2*)dst)[i] = o;
}

// ---- token layer 1 (MFMA, no LDS, split-K): Pt[kc] = t-chunk @ Wt1^T -------
__global__ __launch_bounds__(256) void token1_mfma(
    const ushort* __restrict__ Tb, const ushort* __restrict__ Wt1b,
    float* __restrict__ Pt) {
  const int ct = blockIdx.x, kc = blockIdx.y;
  const int tid = threadIdx.x, l = tid & 63, wv = tid >> 6;
  const int lr = l & 15, ko = l >> 4;
  const int col = ct * 64 + wv * 16 + lr;
  f32x4 acc[4];
#pragma unroll
  for (int r = 0; r < 4; ++r) acc[r] = (f32x4){0.f, 0.f, 0.f, 0.f};
  const int k0 = kc * 384;
#pragma unroll 4
  for (int ks = 0; ks < 12; ++ks) {
    const int k = k0 + ks * 32 + ko * 8;
    const s16x8 bf = *(const s16x8*)(Wt1b + (size_t)col * 1536 + k);
#pragma unroll
    for (int rf = 0; rf < 4; ++rf) {
      const s16x8 af = *(const s16x8*)(Tb + (size_t)(rf * 16 + lr) * 1536 + k);
      acc[rf] =
          __builtin_amdgcn_mfma_f32_16x16x32_bf16(af, bf, acc[rf], 0, 0, 0);
    }
  }
#pragma unroll
  for (int rf = 0; rf < 4; ++rf)
#pragma unroll
    for (int j = 0; j < 4; ++j) {
      const int row = rf * 16 + ko * 4 + j;
      Pt[((kc * 64 + row) << 9) + col] = acc[rf][j];
    }
}

// ---- token layer-1 reduce: Hb[64][512] bf16 = relu(sum_kc Pt + bt1) --------
__global__ __launch_bounds__(256) void token1_reduce(
    const float* __restrict__ Pt, const float* __restrict__ bt1,
    ushort* __restrict__ Hb) {
  const int i = blockIdx.x * 256 + threadIdx.x;
  const int row = i >> 8, c2 = (i & 255) * 2;
  float v0 = bt1[c2], v1 = bt1[c2 + 1];
#pragma unroll
  for (int kc = 0; kc < 4; ++kc) {
    v0 += Pt[((kc * 64 + row) << 9) + c2];
    v1 += Pt[((kc * 64 + row) << 9) + c2 + 1];
  }
  v0 = fmaxf(v0, 0.f);
  v1 = fmaxf(v1, 0.f);
  ((unsigned*)Hb)[i] = pack_bf16x2(v0, v1);
}

// ---- token layer 2 (MFMA, no LDS): TK[64][256] f32 = Hb @ Wt2^T + bt2 ------
__global__ __launch_bounds__(256) void token2_mfma(
    const ushort* __restrict__ Hb, const ushort* __restrict__ Wt2b,
    const float* __restrict__ bt2, float* __restrict__ TK) {
  const int ct = blockIdx.x;
  const int tid = threadIdx.x, l = tid & 63, wv = tid >> 6;
  const int lr = l & 15, ko = l >> 4;
  const int col = ct * 64 + wv * 16 + lr;
  f32x4 acc[4];
#pragma unroll
  for (int r = 0; r < 4; ++r) acc[r] = (f32x4){0.f, 0.f, 0.f, 0.f};
#pragma unroll 4
  for (int ks = 0; ks < 16; ++ks) {
    const int k = ks * 32 + ko * 8;
    const s16x8 bf = *(const s16x8*)(Wt2b + (size_t)col * 512 + k);
#pragma unroll
    for (int rf = 0; rf < 4; ++rf) {
      const s16x8 af = *(const s16x8*)(Hb + (size_t)(rf * 16 + lr) * 512 + k);
      acc[rf] =
          __builtin_amdgcn_mfma_f32_16x16x32_bf16(af, bf, acc[rf], 0, 0, 0);
    }
  }
  const float bb = bt2[col];
#pragma unroll
  for (int rf = 0; rf < 4; ++rf)
#pragma unroll
    for (int j = 0; j < 4; ++j)
      TK[(rf * 16 + ko * 4 + j) * 256 + col] = acc[rf][j] + bb;
}

// ------- x [64][1536][256] fp32 -> XT [16384][1536] bf16 (transpose) --------
// LDS-staged: coalesced reads, XOR-swizzled 16B-granule tile, wave writes
// 8x128B contiguous chunks (no 16B-at-3KB-stride write amplification).
__global__ __launch_bounds__(256) void transpose_x_bf16(
    const float* __restrict__ x, ushort* __restrict__ XT) {
  __shared__ ushort lds[16384];  // 256 tokens x 64 ch (32 KB)
  const int cc = blockIdx.x * 64, b = blockIdx.y;
  const int t = threadIdx.x;
  const float* xb = x + b * 393216 + cc * 256;
#pragma unroll
  for (int i = 0; i < 16; ++i) {
    const int c0 = i * 4;
    const float v0 = xb[(c0 + 0) * 256 + t];
    const float v1 = xb[(c0 + 1) * 256 + t];
    const float v2 = xb[(c0 + 2) * 256 + t];
    const float v3 = xb[(c0 + 3) * 256 + t];
    uint2 o;
    o.x = pack_bf16x2(v0, v1);
    o.y = pack_bf16x2(v2, v3);
    const int g = c0 >> 3;  // 16B granule within the token row
    const int waddr = t * 128 + (((g ^ (t & 7)) << 4) | ((c0 & 7) << 1));
    *(uint2*)((char*)lds + waddr) = o;
  }
  __syncthreads();
#pragma unroll
  for (int r = 0; r < 8; ++r) {
    const int j = r * 32 + (t >> 3), q = t & 7;
    const uint4 o =
        *(const uint4*)((const char*)lds + j * 128 + ((q ^ (j & 7)) << 4));
    *(uint4*)(XT + (size_t)(b * 256 + j) * 1536 + cc + q * 8) = o;
  }
}

// ---- layer-1 MFMA GEMM (fused cluster+score), XCD-swizzled grid ------------
// HT[j][h] = bf16(relu(A1[h]·XT[j] + b1[h])), A1 [1024][1536] stacked.
// grid 1024 linear; newid = (bid%8)*128 + bid/8 pins each XT panel's 8
// m-tiles to ONE XCD, time-adjacent (T1; kills the 4x XT refetch).
__global__ __launch_bounds__(256) void gemm1_mfma(
    const ushort* __restrict__ A1, const ushort* __restrict__ Bt,
    const float* __restrict__ b1, ushort* __restrict__ HT) {
  constexpr int K = 1536;
  __shared__ ushort As[128 * 32];
  __shared__ ushort Bs[128 * 32];
  const int tid = threadIdx.x;
  const int l = tid & 63, w = tid >> 6;
  const int bid = blockIdx.x;
  const int newid = (bid & 7) * 128 + (bid >> 3);
  const int m0 = (newid & 7) * 128, n0 = (newid >> 3) * 128;
  const int wr = w >> 1, wc = w & 1;
  const int lr = l & 15, kq = l >> 4;

  f32x4 acc[4][4];
#pragma unroll
  for (int mi = 0; mi < 4; ++mi)
#pragma unroll
    for (int ni = 0; ni < 4; ++ni) acc[mi][ni] = (f32x4){0.f, 0.f, 0.f, 0.f};

  const int rA0 = tid >> 2;
  const int q8 = (tid & 3) * 8;
  ushort* AsW0 = As + (w * 64) * 8;
  ushort* AsW1 = As + (256 + w * 64) * 8;
  ushort* BsW0 = Bs + (w * 64) * 8;
  ushort* BsW1 = Bs + (256 + w * 64) * 8;
  const ushort* Arow0 = A1 + (size_t)(m0 + rA0) * K + q8;
  const ushort* Arow1 = A1 + (size_t)(m0 + rA0 + 64) * K + q8;
  const ushort* Brow0 = Bt + (size_t)(n0 + rA0) * K + q8;
  const ushort* Brow1 = Bt + (size_t)(n0 + rA0 + 64) * K + q8;

  for (int k0 = 0; k0 < K; k0 += 32) {
    __syncthreads();
    gload_lds16(Arow0 + k0, AsW0);
    gload_lds16(Arow1 + k0, AsW1);
    gload_lds16(Brow0 + k0, BsW0);
    gload_lds16(Brow1 + k0, BsW1);
    __syncthreads();
    s16x8 af[4], bfr[4];
#pragma unroll
    for (int mi = 0; mi < 4; ++mi)
      af[mi] = *(const s16x8*)(As + (wr * 64 + mi * 16 + lr) * 32 + kq * 8);
#pragma unroll
    for (int ni = 0; ni < 4; ++ni)
      bfr[ni] = *(const s16x8*)(Bs + (wc * 64 + ni * 16 + lr) * 32 + kq * 8);
#pragma unroll
    for (int mi = 0; mi < 4; ++mi)
#pragma unroll
      for (int ni = 0; ni < 4; ++ni)
        acc[mi][ni] = __builtin_amdgcn_mfma_f32_16x16x32_bf16(
            af[mi], bfr[ni], acc[mi][ni], 0, 0, 0);
  }

#pragma unroll
  for (int mi = 0; mi < 4; ++mi) {
    const int rbase = m0 + wr * 64 + mi * 16 + kq * 4;
    float b4[4];
#pragma unroll
    for (int j = 0; j < 4; ++j) b4[j] = b1[rbase + j];
#pragma unroll
    for (int ni = 0; ni < 4; ++ni) {
      const int col = n0 + wc * 64 + ni * 16 + lr;
      const float v0 = fmaxf(acc[mi][ni][0] + b4[0], 0.f);
      const float v1 = fmaxf(acc[mi][ni][1] + b4[1], 0.f);
      const float v2 = fmaxf(acc[mi][ni][2] + b4[2], 0.f);
      const float v3 = fmaxf(acc[mi][ni][3] + b4[3], 0.f);
      uint2 o;
      o.x = pack_bf16x2(v0, v1);
      o.y = pack_bf16x2(v2, v3);
      *(uint2*)(HT + (size_t)col * 1024 + rbase) = o;
    }
  }
}

// ---- layer-2 MFMA GEMM: C2[192][BNT] = A2[256][1024] @ HT^T + b2 -----------
// grid 256 linear; XCD-swizzled like gemm1 (HT panel locality).
__global__ __launch_bounds__(256) void gemm2_mfma(
    const ushort* __restrict__ A2, const ushort* __restrict__ HT,
    const float* __restrict__ b2, float* __restrict__ C2) {
  constexpr int K = 1024;
  __shared__ ushort As[128 * 32];
  __shared__ ushort Bs[128 * 32];
  const int tid = threadIdx.x;
  const int l = tid & 63, w = tid >> 6;
  const int bid = blockIdx.x;
  const int newid = (bid & 7) * 32 + (bid >> 3);
  const int m0 = (newid & 1) * 128, n0 = (newid >> 1) * 128;
  const int wr = w >> 1, wc = w & 1;
  const int lr = l & 15, kq = l >> 4;

  f32x4 acc[4][4];
#pragma unroll
  for (int mi = 0; mi < 4; ++mi)
#pragma unroll
    for (int ni = 0; ni < 4; ++ni) acc[mi][ni] = (f32x4){0.f, 0.f, 0.f, 0.f};

  const int rA0 = tid >> 2;
  const int q8 = (tid & 3) * 8;
  ushort* AsW0 = As + (w * 64) * 8;
  ushort* AsW1 = As + (256 + w * 64) * 8;
  ushort* BsW0 = Bs + (w * 64) * 8;
  ushort* BsW1 = Bs + (256 + w * 64) * 8;
  const ushort* Arow0 = A2 + (size_t)(m0 + rA0) * K + q8;
  const ushort* Arow1 = A2 + (size_t)(m0 + rA0 + 64) * K + q8;
  const ushort* Brow0 = HT + (size_t)(n0 + rA0) * K + q8;
  const ushort* Brow1 = HT + (size_t)(n0 + rA0 + 64) * K + q8;

  for (int k0 = 0; k0 < K; k0 += 32) {
    __syncthreads();
    gload_lds16(Arow0 + k0, AsW0);
    gload_lds16(Arow1 + k0, AsW1);
    gload_lds16(Brow0 + k0, BsW0);
    gload_lds16(Brow1 + k0, BsW1);
    __syncthreads();
    s16x8 af[4], bfr[4];
#pragma unroll
    for (int mi = 0; mi < 4; ++mi)
      af[mi] = *(const s16x8*)(As + (wr * 64 + mi * 16 + lr) * 32 + kq * 8);
#pragma unroll
    for (int ni = 0; ni < 4; ++ni)
      bfr[ni] = *(const s16x8*)(Bs + (wc * 64 + ni * 16 + lr) * 32 + kq * 8);
#pragma unroll
    for (int mi = 0; mi < 4; ++mi)
#pragma unroll
      for (int ni = 0; ni < 4; ++ni)
        acc[mi][ni] = __builtin_amdgcn_mfma_f32_16x16x32_bf16(
            af[mi], bfr[ni], acc[mi][ni], 0, 0, 0);
  }

#pragma unroll
  for (int mi = 0; mi < 4; ++mi) {
    const int rbase = m0 + wr * 64 + mi * 16 + kq * 4;
    if (rbase < 192) {
      float b4[4];
#pragma unroll
      for (int j = 0; j < 4; ++j) b4[j] = b2[rbase + j];
#pragma unroll
      for (int ni = 0; ni < 4; ++ni) {
        const int col = n0 + wc * 64 + ni * 16 + lr;
        float* cr = C2 + (size_t)rbase * BNT + col;
#pragma unroll
        for (int j = 0; j < 4; ++j) cr[(size_t)j * BNT] = acc[mi][ni][j] + b4[j];
      }
    }
  }
}

// ---------------- fp32 GEMMs (fallback path only) ---------------------------
template <bool RELU>
__global__ __launch_bounds__(256) void gemm_tt(
    const float* __restrict__ A, const float* __restrict__ Bw,
    const float* __restrict__ bias, float* __restrict__ C, int K, int Nn) {
  __shared__ float As[16][68];
  __shared__ float Bs[16][68];
  const int tid = threadIdx.x;
  const int tx = tid & 15, ty = tid >> 4;
  const int n0 = blockIdx.x * 64;
  const int lrow = tid >> 2, lkq = (tid & 3) << 2;
  float acc[4][4];
#pragma unroll
  for (int r = 0; r < 4; ++r)
#pragma unroll
    for (int c = 0; c < 4; ++c) acc[r][c] = 0.f;
  for (int k0 = 0; k0 < K; k0 += 16) {
    const float4 av = *(const float4*)&A[lrow * K + k0 + lkq];
    const float4 bv = *(const float4*)&Bw[(n0 + lrow) * K + k0 + lkq];
    As[lkq + 0][lrow] = av.x;
    As[lkq + 1][lrow] = av.y;
    As[lkq + 2][lrow] = av.z;
    As[lkq + 3][lrow] = av.w;
    Bs[lkq + 0][lrow] = bv.x;
    Bs[lkq + 1][lrow] = bv.y;
    Bs[lkq + 2][lrow] = bv.z;
    Bs[lkq + 3][lrow] = bv.w;
    __syncthreads();
#pragma unroll
    for (int kk = 0; kk < 16; ++kk) {
      const float4 a4 = *(const float4*)&As[kk][ty << 2];
      const float4 b4 = *(const float4*)&Bs[kk][tx << 2];
      acc[0][0] = fmaf(a4.x, b4.x, acc[0][0]);
      acc[0][1] = fmaf(a4.x, b4.y, acc[0][1]);
      acc[0][2] = fmaf(a4.x, b4.z, acc[0][2]);
      acc[0][3] = fmaf(a4.x, b4.w, acc[0][3]);
      acc[1][0] = fmaf(a4.y, b4.x, acc[1][0]);
      acc[1][1] = fmaf(a4.y, b4.y, acc[1][1]);
      acc[1][2] = fmaf(a4.y, b4.z, acc[1][2]);
      acc[1][3] = fmaf(a4.y, b4.w, acc[1][3]);
      acc[2][0] = fmaf(a4.z, b4.x, acc[2][0]);
      acc[2][1] = fmaf(a4.z, b4.y, acc[2][1]);
      acc[2][2] = fmaf(a4.z, b4.z, acc[2][2]);
      acc[2][3] = fmaf(a4.z, b4.w, acc[2][3]);
      acc[3][0] = fmaf(a4.w, b4.x, acc[3][0]);
      acc[3][1] = fmaf(a4.w, b4.y, acc[3][1]);
      acc[3][2] = fmaf(a4.w, b4.z, acc[3][2]);
      acc[3][3] = fmaf(a4.w, b4.w, acc[3][3]);
    }
    __syncthreads();
  }
#pragma unroll
  for (int r = 0; r < 4; ++r) {
    const int row = (ty << 2) + r;
    float4 o;
    o.x = acc[r][0] + bias[n0 + (tx << 2) + 0];
    o.y = acc[r][1] + bias[n0 + (tx << 2) + 1];
    o.z = acc[r][2] + bias[n0 + (tx << 2) + 2];
    o.w = acc[r][3] + bias[n0 + (tx << 2) + 3];
    if (RELU) {
      o.x = fmaxf(o.x, 0.f);
      o.y = fmaxf(o.y, 0.f);
      o.z = fmaxf(o.z, 0.f);
      o.w = fmaxf(o.w, 0.f);
    }
    *(float4*)&C[row * Nn + n0 + (tx << 2)] = o;
  }
}

template <bool XVIEW, bool RELU>
__global__ __launch_bounds__(256) void gemm_tile(
    const float* __restrict__ A, const float* __restrict__ Bsrc,
    const float* __restrict__ bias, float* __restrict__ Cout, int K) {
  __shared__ float As[16][68];
  __shared__ float Bsh[16][68];
  const int tid = threadIdx.x;
  const int tx = tid & 15, ty = tid >> 4;
  const int rowBase = blockIdx.y * 64;
  const int colBase = blockIdx.x * 64;
  const int bb = colBase >> 8, n0 = colBase & 255;
  const int boff = XVIEW ? (bb * 393216 + n0) : colBase;
  const int la_row = tid >> 2, la_kq = (tid & 3) << 2;
  const int lb_k = tid >> 4, lb_c = (tid & 15) << 2;
  float acc[4][4];
#pragma unroll
  for (int r = 0; r < 4; ++r)
#pragma unroll
    for (int c = 0; c < 4; ++c) acc[r][c] = 0.f;
  for (int k0 = 0; k0 < K; k0 += 16) {
    const float4 av = *(const float4*)&A[(rowBase + la_row) * K + k0 + la_kq];
    float4 bv;
    if (XVIEW)
      bv = *(const float4*)&Bsrc[boff + (k0 + lb_k) * 256 + lb_c];
    else
      bv = *(const float4*)&Bsrc[(k0 + lb_k) * BNT + boff + lb_c];
    As[la_kq + 0][la_row] = av.x;
    As[la_kq + 1][la_row] = av.y;
    As[la_kq + 2][la_row] = av.z;
    As[la_kq + 3][la_row] = av.w;
    *(float4*)&Bsh[lb_k][lb_c] = bv;
    __syncthreads();
#pragma unroll
    for (int kk = 0; kk < 16; ++kk) {
      const float4 a4 = *(const float4*)&As[kk][ty << 2];
      const float4 b4 = *(const float4*)&Bsh[kk][tx << 2];
      acc[0][0] = fmaf(a4.x, b4.x, acc[0][0]);
      acc[0][1] = fmaf(a4.x, b4.y, acc[0][1]);
      acc[0][2] = fmaf(a4.x, b4.z, acc[0][2]);
      acc[0][3] = fmaf(a4.x, b4.w, acc[0][3]);
      acc[1][0] = fmaf(a4.y, b4.x, acc[1][0]);
      acc[1][1] = fmaf(a4.y, b4.y, acc[1][1]);
      acc[1][2] = fmaf(a4.y, b4.z, acc[1][2]);
      acc[1][3] = fmaf(a4.y, b4.w, acc[1][3]);
      acc[2][0] = fmaf(a4.z, b4.x, acc[2][0]);
      acc[2][1] = fmaf(a4.z, b4.y, acc[2][1]);
      acc[2][2] = fmaf(a4.z, b4.z, acc[2][2]);
      acc[2][3] = fmaf(a4.z, b4.w, acc[2][3]);
      acc[3][0] = fmaf(a4.w, b4.x, acc[3][0]);
      acc[3][1] = fmaf(a4.w, b4.y, acc[3][1]);
      acc[3][2] = fmaf(a4.w, b4.z, acc[3][2]);
      acc[3][3] = fmaf(a4.w, b4.w, acc[3][3]);
    }
    __syncthreads();
  }
#pragma unroll
  for (int r = 0; r < 4; ++r) {
    const int row = rowBase + (ty << 2) + r;
    const float bsv = bias[row];
    float4 o;
    o.x = acc[r][0] + bsv;
    o.y = acc[r][1] + bsv;
    o.z = acc[r][2] + bsv;
    o.w = acc[r][3] + bsv;
    if (RELU) {
      o.x = fmaxf(o.x, 0.f);
      o.y = fmaxf(o.y, 0.f);
      o.z = fmaxf(o.z, 0.f);
      o.w = fmaxf(o.w, 0.f);
    }
    *(float4*)&Cout[row * BNT + colBase + (tx << 2)] = o;
  }
}

// ---------------- Sinkhorn (log domain, 3 iters, dustbin row) ----------------
__global__ __launch_bounds__(256) void sinkhorn_kernel(
    const float* __restrict__ S, const float* __restrict__ dustp,
    float* __restrict__ P) {
  const int b = blockIdx.x, tid = threadIdx.x;
  const int lane = tid & 63, wave = tid >> 6;
  __shared__ float Ms[65][256];
  __shared__ float u[65];
  __shared__ float v[256];
  const float dust = dustp[0];
  for (int idx = tid; idx < 16384; idx += 256) {
    const int m = idx >> 8, n = idx & 255;
    Ms[m][n] = S[m * BNT + b * 256 + n];
  }
  Ms[64][tid] = dust;
  v[tid] = 0.f;
  if (tid < 65) u[tid] = 0.f;
  const float norm = -logf(320.f);
  const float la_dust = norm + logf(192.f);
  __syncthreads();
  for (int it = 0; it < 3; ++it) {
    for (int i = wave; i < 65; i += 4) {
      const float x0 = Ms[i][lane] + v[lane];
      const float x1 = Ms[i][lane + 64] + v[lane + 64];
      const float x2 = Ms[i][lane + 128] + v[lane + 128];
      const float x3 = Ms[i][lane + 192] + v[lane + 192];
      float mm = fmaxf(fmaxf(x0, x1), fmaxf(x2, x3));
#pragma unroll
      for (int off = 32; off; off >>= 1) mm = fmaxf(mm, __shfl_xor(mm, off));
      float s = expf(x0 - mm) + expf(x1 - mm) + expf(x2 - mm) + expf(x3 - mm);
#pragma unroll
      for (int off = 32; off; off >>= 1) s += __shfl_xor(s, off);
      if (lane == 0) u[i] = (i == 64 ? la_dust : norm) - (logf(s) + mm);
    }
    __syncthreads();
    {
      const int n = tid;
      float mm = -1e30f;
      for (int i = 0; i < 65; ++i) mm = fmaxf(mm, Ms[i][n] + u[i]);
      float s = 0.f;
      for (int i = 0; i < 65; ++i) s += expf(Ms[i][n] + u[i] - mm);
      v[n] = norm - (logf(s) + mm);
    }
    __syncthreads();
  }
  for (int idx = tid; idx < 16384; idx += 256) {
    const int m = idx >> 8, n = idx & 255;
    P[b * 16384 + idx] = expf(Ms[m][n] + u[m] + v[n] - norm);
  }
}

// ---------------- VLAD ------------------------------------------------------
__device__ __forceinline__ int ps_idx(int m, int n) {
  return m * 256 + ((((n >> 2) ^ (m & 7)) << 2) | (n & 3));
}
__global__ __launch_bounds__(256) void vlad_kernel(const float* __restrict__ F,
                                                   const float* __restrict__ P,
                                                   float* __restrict__ VL) {
  const int b = blockIdx.x, half = blockIdx.y;
  const int tid = threadIdx.x;
  const int m = tid & 63, lg = tid >> 6;
  __shared__ float ps[64 * 256];
  for (int idx = tid; idx < 16384; idx += 256) {
    const int mm = idx >> 8, n = idx & 255;
    ps[ps_idx(mm, n)] = P[b * 16384 + idx];
  }
  __syncthreads();
  float acc[16];
#pragma unroll
  for (int i = 0; i < 16; ++i) acc[i] = 0.f;
  for (int i = 0; i < 16; ++i) {
    const int ll = half * 64 + lg + 4 * i;
    const float* frow = &F[(size_t)ll * BNT + b * 256];
    float a = 0.f;
#pragma unroll 8
    for (int nq = 0; nq < 64; ++nq) {
      const float4 f4 = *(const float4*)&frow[nq << 2];
      const float4 p4 = *(const float4*)&ps[m * 256 + ((nq ^ (m & 7)) << 2)];
      a = fmaf(f4.x, p4.x, a);
      a = fmaf(f4.y, p4.y, a);
      a = fmaf(f4.z, p4.z, a);
      a = fmaf(f4.w, p4.w, a);
    }
    acc[i] = a;
  }
#pragma unroll
  for (int i = 0; i < 16; ++i) {
    const int ll = half * 64 + lg + 4 * i;
    VL[b * 8192 + ll * 64 + m] = acc[i];
  }
}

// ---------------- finalize ---------------------------------------------------
__global__ __launch_bounds__(256) void finalize_kernel(
    const float* __restrict__ TK, const float* __restrict__ VL,
    float* __restrict__ out) {
  const int b = blockIdx.x, tid = threadIdx.x;
  const int lane = tid & 63, wave = tid >> 6;
  __shared__ float sred[4];
  __shared__ float ssm_part[4][64];
  __shared__ float invm_s[64];
  __shared__ float totals[1];
  const float* vl = &VL[b * 8192];
  float accv = 0.f;
  for (int k = 0; k < 32; ++k) {
    const float xv = vl[tid + 256 * k];
    accv = fmaf(xv, xv, accv);
  }
  ssm_part[wave][lane] = accv;
  const float tv = TK[b * 256 + tid];
  float ss = tv * tv;
#pragma unroll
  for (int off = 32; off; off >>= 1) ss += __shfl_down(ss, off);
  if (lane == 0) sred[wave] = ss;
  __syncthreads();
  const float sstok = sred[0] + sred[1] + sred[2] + sred[3];
  const float invtok = 1.f / fmaxf(sqrtf(sstok), 1e-12f);
  float tpart = 0.f;
  if (wave == 0) {
    const float s4 = ssm_part[0][tid] + ssm_part[1][tid] + ssm_part[2][tid] +
                     ssm_part[3][tid];
    const float inv = 1.f / fmaxf(sqrtf(s4), 1e-12f);
    invm_s[tid] = inv;
    tpart = s4 * inv * inv;
#pragma unroll
    for (int off = 32; off; off >>= 1) tpart += __shfl_down(tpart, off);
    if (lane == 0) totals[0] = tpart;
  }
  __syncthreads();
  const float total = totals[0] + sstok * invtok * invtok;
  const float invT = 1.f / fmaxf(sqrtf(total), 1e-12f);
  float* ob = &out[b * 8448];
  ob[tid] = tv * invtok * invT;
  for (int k = 0; k < 32; ++k) {
    const int idx = tid + 256 * k;
    ob[256 + idx] = vl[idx] * invm_s[idx & 63] * invT;
  }
}

extern "C" void kernel_launch(void* const* d_in, const int* in_sizes, int n_in,
                              void* d_out, int out_size, void* d_ws,
                              size_t ws_size, hipStream_t stream) {
  const float* x = (const float*)d_in[0];
  const float* t = (const float*)d_in[1];
  const float* Wt1 = (const float*)d_in[2];
  const float* bt1 = (const float*)d_in[3];
  const float* Wt2 = (const float*)d_in[4];
  const float* bt2 = (const float*)d_in[5];
  const float* Wc1 = (const float*)d_in[6];
  const float* bc1 = (const float*)d_in[7];
  const float* Wc2 = (const float*)d_in[8];
  const float* bc2 = (const float*)d_in[9];
  const float* Ws1 = (const float*)d_in[10];
  const float* bs1 = (const float*)d_in[11];
  const float* Ws2 = (const float*)d_in[12];
  const float* bs2 = (const float*)d_in[13];
  const float* dust = (const float*)d_in[14];
  float* out = (float*)d_out;

  if (ws_size >= 97714176ull) {
    // Byte layout (stream-ordered overlays):
    // [0, 50331648)        XT bf16 16384x1536
    //   pre-transpose overlay (token scratch): Tb@0, Wt1b@196608,
    //     Wt2b@1769472, Pt@2031616, Hb@2555904
    //   post-gemm1 overlay: P@0, VL@4194304
    // [50331648, 83886080) HT bf16 16384x1024
    // [83886080, 96468992) C2 f32 192xBNT; pre-gemm2 overlay: A1 stacked
    //                      (Wc1b@83886080, Ws1b@85458944)
    // [96468992, 96993280) A2 bf16 256x1024
    // [96993280, 96994304) b2 f32 256
    // [96994304, 97059840) TK f32 64x256
    // [97059840, 97063936) b1 f32 1024
    char* base = (char*)d_ws;
    ushort* Tb = (ushort*)base;
    ushort* Wt1b = (ushort*)(base + 196608);
    ushort* Wt2b = (ushort*)(base + 1769472);
    float* Pt = (float*)(base + 2031616);
    ushort* Hb = (ushort*)(base + 2555904);
    ushort* XT = (ushort*)base;
    float* P = (float*)base;
    float* VL = (float*)(base + 4194304);
    ushort* HT = (ushort*)(base + 50331648);
    float* C2 = (float*)(base + 83886080);
    ushort* A1 = (ushort*)(base + 83886080);
    ushort* Wc1b = A1;
    ushort* Ws1b = (ushort*)(base + 85458944);
    ushort* A2 = (ushort*)(base + 96468992);
    float* b2 = (float*)(base + 96993280);
    float* TK = (float*)(base + 96994304);
    float* b1 = (float*)(base + 97059840);
    float* F = C2;                       // rows 0..127
    float* Sb = C2 + (size_t)128 * BNT;  // rows 128..191

    prep_all<<<2788, 256, 0, stream>>>(t, Wt1, Wt2, Wc1, Ws1, bc1, bs1, Wc2,
                                       Ws2, bc2, bs2, Tb, Wt1b, Wt2b, Wc1b,
                                       Ws1b, b1, A2, b2);
    token1_mfma<<<dim3(8, 4), 256, 0, stream>>>(Tb, Wt1b, Pt);
    token1_reduce<<<64, 256, 0, stream>>>(Pt, bt1, Hb);
    token2_mfma<<<4, 256, 0, stream>>>(Hb, Wt2b, bt2, TK);
    transpose_x_bf16<<<dim3(24, 64), 256, 0, stream>>>(x, XT);
    gemm1_mfma<<<1024, 256, 0, stream>>>(A1, XT, b1, HT);
    gemm2_mfma<<<256, 256, 0, stream>>>(A2, HT, b2, C2);
    sinkhorn_kernel<<<64, 256, 0, stream>>>(Sb, dust, P);
    vlad_kernel<<<dim3(64, 2), 256, 0, stream>>>(F, P, VL);
    finalize_kernel<<<64, 256, 0, stream>>>(TK, VL, out);
  } else {
    // fp32 fallback (fits 52.6 MB)
    float* ws = (float*)d_ws;
    float* H = ws;
    float* F = H + 512 * BNT;
    float* Sb = F + 128 * BNT;
    float* P = Sb + 64 * BNT;
    float* VL = P + 64 * BNT;
    float* TK = VL + 64 * 8192;
    float* Hh = P;

    gemm_tt<true><<<dim3(8, 1), 256, 0, stream>>>(t, Wt1, bt1, Hh, 1536, 512);
    gemm_tt<false><<<dim3(4, 1), 256, 0, stream>>>(Hh, Wt2, bt2, TK, 512, 256);
    gemm_tile<true, true><<<dim3(256, 8), 256, 0, stream>>>(Wc1, x, bc1, H, 1536);
    gemm_tile<false, false><<<dim3(256, 2), 256, 0, stream>>>(Wc2, H, bc2, F, 512);
    gemm_tile<true, true><<<dim3(256, 8), 256, 0, stream>>>(Ws1, x, bs1, H, 1536);
    gemm_tile<false, false><<<dim3(256, 1), 256, 0, stream>>>(Ws2, H, bs2, Sb, 512);
    sinkhorn_kernel<<<64, 256, 0, stream>>>(Sb, dust, P);
    vlad_kernel<<<dim3(64, 2), 256, 0, stream>>>(F, P, VL);
    finalize_kernel<<<64, 256, 0, stream>>>(TK, VL, out);
  }
}

// Round 7
// 218.454 us; speedup vs baseline: 7.9060x; 1.1784x over previous
//
#include <hip/hip_runtime.h>
#include <math.h>

// SALAD head. B=64, C=1536, N=256, HID=512, L=128, M=64, G=256. BNT = B*N.
#define BNT 16384

using f32x4 = __attribute__((ext_vector_type(4))) float;
using s16x8 = __attribute__((ext_vector_type(8))) short;

__device__ __forceinline__ unsigned short f32_to_bf16_rne(float f) {
  unsigned int u = __float_as_uint(f);
  u += 0x7FFFu + ((u >> 16) & 1u);
  return (unsigned short)(u >> 16);
}
__device__ __forceinline__ unsigned pack_bf16x2(float a, float b) {
  return (unsigned)f32_to_bf16_rne(a) | ((unsigned)f32_to_bf16_rne(b) << 16);
}

__device__ __forceinline__ void gload_lds16(const ushort* g, ushort* lds) {
  __builtin_amdgcn_global_load_lds(
      (const __attribute__((address_space(1))) unsigned int*)g,
      (__attribute__((address_space(3))) unsigned int*)lds, 16, 0, 0);
}

// ---- fused prep: bf16 converts of t,Wt1,Wt2,Wc1,Ws1 + b1 stack + A2 stack --
__global__ __launch_bounds__(256) void prep_all(
    const float* __restrict__ t, const float* __restrict__ Wt1,
    const float* __restrict__ Wt2, const float* __restrict__ Wc1,
    const float* __restrict__ Ws1, const float* __restrict__ bc1,
    const float* __restrict__ bs1, const float* __restrict__ Wc2,
    const float* __restrict__ Ws2, const float* __restrict__ bc2,
    const float* __restrict__ bs2, ushort* __restrict__ Tb,
    ushort* __restrict__ Wt1b, ushort* __restrict__ Wt2b,
    ushort* __restrict__ Wc1b, ushort* __restrict__ Ws1b,
    float* __restrict__ b1, ushort* __restrict__ A2, float* __restrict__ b2) {
  const int bid = blockIdx.x, tid = threadIdx.x;
  const float* src = nullptr;
  ushort* dst = nullptr;
  int i = 0;
  if (bid < 96) {
    src = t; dst = Tb; i = bid * 256 + tid;
  } else if (bid < 864) {
    src = Wt1; dst = Wt1b; i = (bid - 96) * 256 + tid;
  } else if (bid < 992) {
    src = Wt2; dst = Wt2b; i = (bid - 864) * 256 + tid;
  } else if (bid < 1760) {
    src = Wc1; dst = Wc1b; i = (bid - 992) * 256 + tid;
  } else if (bid < 2528) {
    src = Ws1; dst = Ws1b; i = (bid - 1760) * 256 + tid;
  } else if (bid < 2532) {
    const int j = (bid - 2528) * 256 + tid;
    b1[j] = j < 512 ? bc1[j] : bs1[j - 512];
    return;
  } else {
    const int r = bid - 2532;
    const int c = tid * 4;
    float v[4] = {0.f, 0.f, 0.f, 0.f};
    if (r < 128) {
      if (c < 512) {
#pragma unroll
        for (int j = 0; j < 4; ++j) v[j] = Wc2[r * 512 + c + j];
      }
    } else if (r < 192) {
      if (c >= 512) {
#pragma unroll
        for (int j = 0; j < 4; ++j) v[j] = Ws2[(r - 128) * 512 + (c - 512) + j];
      }
    }
    uint2 o;
    o.x = pack_bf16x2(v[0], v[1]);
    o.y = pack_bf16x2(v[2], v[3]);
    *(uint2*)(A2 + r * 1024 + c) = o;
    if (tid == 0) b2[r] = r < 128 ? bc2[r] : (r < 192 ? bs2[r - 128] : 0.f);
    return;
  }
  const float4 v = ((const float4*)src)[i];
  uint2 o;
  o.x = pack_bf16x2(v.x, v.y);
  o.y = pack_bf16x2(v.z, v.w);
  ((uint2*)dst)[i] = o;
}

// ---- token layer 1 (MFMA, no LDS, split-K): Pt[kc] = t-chunk @ Wt1^T -------
__global__ __launch_bounds__(256) void token1_mfma(
    const ushort* __restrict__ Tb, const ushort* __restrict__ Wt1b,
    float* __restrict__ Pt) {
  const int ct = blockIdx.x, kc = blockIdx.y;
  const int tid = threadIdx.x, l = tid & 63, wv = tid >> 6;
  const int lr = l & 15, ko = l >> 4;
  const int col = ct * 64 + wv * 16 + lr;
  f32x4 acc[4];
#pragma unroll
  for (int r = 0; r < 4; ++r) acc[r] = (f32x4){0.f, 0.f, 0.f, 0.f};
  const int k0 = kc * 384;
#pragma unroll 4
  for (int ks = 0; ks < 12; ++ks) {
    const int k = k0 + ks * 32 + ko * 8;
    const s16x8 bf = *(const s16x8*)(Wt1b + (size_t)col * 1536 + k);
#pragma unroll
    for (int rf = 0; rf < 4; ++rf) {
      const s16x8 af = *(const s16x8*)(Tb + (size_t)(rf * 16 + lr) * 1536 + k);
      acc[rf] =
          __builtin_amdgcn_mfma_f32_16x16x32_bf16(af, bf, acc[rf], 0, 0, 0);
    }
  }
#pragma unroll
  for (int rf = 0; rf < 4; ++rf)
#pragma unroll
    for (int j = 0; j < 4; ++j) {
      const int row = rf * 16 + ko * 4 + j;
      Pt[((kc * 64 + row) << 9) + col] = acc[rf][j];
    }
}

// ---- token layer-1 reduce: Hb[64][512] bf16 = relu(sum_kc Pt + bt1) --------
__global__ __launch_bounds__(256) void token1_reduce(
    const float* __restrict__ Pt, const float* __restrict__ bt1,
    ushort* __restrict__ Hb) {
  const int i = blockIdx.x * 256 + threadIdx.x;
  const int row = i >> 8, c2 = (i & 255) * 2;
  float v0 = bt1[c2], v1 = bt1[c2 + 1];
#pragma unroll
  for (int kc = 0; kc < 4; ++kc) {
    v0 += Pt[((kc * 64 + row) << 9) + c2];
    v1 += Pt[((kc * 64 + row) << 9) + c2 + 1];
  }
  v0 = fmaxf(v0, 0.f);
  v1 = fmaxf(v1, 0.f);
  ((unsigned*)Hb)[i] = pack_bf16x2(v0, v1);
}

// ---- token layer 2 (MFMA, no LDS): TK[64][256] f32 = Hb @ Wt2^T + bt2 ------
__global__ __launch_bounds__(256) void token2_mfma(
    const ushort* __restrict__ Hb, const ushort* __restrict__ Wt2b,
    const float* __restrict__ bt2, float* __restrict__ TK) {
  const int ct = blockIdx.x;
  const int tid = threadIdx.x, l = tid & 63, wv = tid >> 6;
  const int lr = l & 15, ko = l >> 4;
  const int col = ct * 64 + wv * 16 + lr;
  f32x4 acc[4];
#pragma unroll
  for (int r = 0; r < 4; ++r) acc[r] = (f32x4){0.f, 0.f, 0.f, 0.f};
#pragma unroll 4
  for (int ks = 0; ks < 16; ++ks) {
    const int k = ks * 32 + ko * 8;
    const s16x8 bf = *(const s16x8*)(Wt2b + (size_t)col * 512 + k);
#pragma unroll
    for (int rf = 0; rf < 4; ++rf) {
      const s16x8 af = *(const s16x8*)(Hb + (size_t)(rf * 16 + lr) * 512 + k);
      acc[rf] =
          __builtin_amdgcn_mfma_f32_16x16x32_bf16(af, bf, acc[rf], 0, 0, 0);
    }
  }
  const float bb = bt2[col];
#pragma unroll
  for (int rf = 0; rf < 4; ++rf)
#pragma unroll
    for (int j = 0; j < 4; ++j)
      TK[(rf * 16 + ko * 4 + j) * 256 + col] = acc[rf][j] + bb;
}

// ------- x [64][1536][256] fp32 -> XT [16384][1536] bf16 (transpose) --------
__global__ __launch_bounds__(256) void transpose_x_bf16(
    const float* __restrict__ x, ushort* __restrict__ XT) {
  __shared__ ushort lds[16384];  // 256 tokens x 64 ch (32 KB)
  const int cc = blockIdx.x * 64, b = blockIdx.y;
  const int t = threadIdx.x;
  const float* xb = x + b * 393216 + cc * 256;
#pragma unroll
  for (int i = 0; i < 16; ++i) {
    const int c0 = i * 4;
    const float v0 = xb[(c0 + 0) * 256 + t];
    const float v1 = xb[(c0 + 1) * 256 + t];
    const float v2 = xb[(c0 + 2) * 256 + t];
    const float v3 = xb[(c0 + 3) * 256 + t];
    uint2 o;
    o.x = pack_bf16x2(v0, v1);
    o.y = pack_bf16x2(v2, v3);
    const int g = c0 >> 3;
    const int waddr = t * 128 + (((g ^ (t & 7)) << 4) | ((c0 & 7) << 1));
    *(uint2*)((char*)lds + waddr) = o;
  }
  __syncthreads();
#pragma unroll
  for (int r = 0; r < 8; ++r) {
    const int j = r * 32 + (t >> 3), q = t & 7;
    const uint4 o =
        *(const uint4*)((const char*)lds + j * 128 + ((q ^ (j & 7)) << 4));
    *(uint4*)(XT + (size_t)(b * 256 + j) * 1536 + cc + q * 8) = o;
  }
}

// ---- layer-1 MFMA GEMM (fused cluster+score), XCD-swizzled, 2-phase dbuf ---
// HT[j][h] = bf16(relu(A1[h]·XT[j] + b1[h])), A1 [1024][1536] stacked.
// Prefetch K-tile t+1 into buf^1 BEFORE compute of tile t; one barrier/step.
__global__ __launch_bounds__(256) void gemm1_mfma(
    const ushort* __restrict__ A1, const ushort* __restrict__ Bt,
    const float* __restrict__ b1, ushort* __restrict__ HT) {
  constexpr int K = 1536;
  __shared__ ushort As[2 * 128 * 32];
  __shared__ ushort Bs[2 * 128 * 32];
  const int tid = threadIdx.x;
  const int l = tid & 63, w = tid >> 6;
  const int bid = blockIdx.x;
  const int newid = (bid & 7) * 128 + (bid >> 3);
  const int m0 = (newid & 7) * 128, n0 = (newid >> 3) * 128;
  const int wr = w >> 1, wc = w & 1;
  const int lr = l & 15, kq = l >> 4;

  f32x4 acc[4][4];
#pragma unroll
  for (int mi = 0; mi < 4; ++mi)
#pragma unroll
    for (int ni = 0; ni < 4; ++ni) acc[mi][ni] = (f32x4){0.f, 0.f, 0.f, 0.f};

  const int rA0 = tid >> 2;
  const int q8 = (tid & 3) * 8;
  ushort* AsW0 = As + (w * 64) * 8;
  ushort* AsW1 = As + (256 + w * 64) * 8;
  ushort* BsW0 = Bs + (w * 64) * 8;
  ushort* BsW1 = Bs + (256 + w * 64) * 8;
  const ushort* Arow0 = A1 + (size_t)(m0 + rA0) * K + q8;
  const ushort* Arow1 = A1 + (size_t)(m0 + rA0 + 64) * K + q8;
  const ushort* Brow0 = Bt + (size_t)(n0 + rA0) * K + q8;
  const ushort* Brow1 = Bt + (size_t)(n0 + rA0 + 64) * K + q8;

  // prologue: stage tile 0 into buffer 0
  gload_lds16(Arow0, AsW0);
  gload_lds16(Arow1, AsW1);
  gload_lds16(Brow0, BsW0);
  gload_lds16(Brow1, BsW1);
  __syncthreads();

  int cur = 0;
  for (int k0 = 0; k0 < K; k0 += 32) {
    const int nxt = cur ^ 1;
    if (k0 + 32 < K) {  // prefetch next tile (overlaps ds_read+MFMA below)
      gload_lds16(Arow0 + k0 + 32, AsW0 + nxt * 4096);
      gload_lds16(Arow1 + k0 + 32, AsW1 + nxt * 4096);
      gload_lds16(Brow0 + k0 + 32, BsW0 + nxt * 4096);
      gload_lds16(Brow1 + k0 + 32, BsW1 + nxt * 4096);
    }
    const ushort* Ab = As + cur * 4096;
    const ushort* Bb = Bs + cur * 4096;
    s16x8 af[4], bfr[4];
#pragma unroll
    for (int mi = 0; mi < 4; ++mi)
      af[mi] = *(const s16x8*)(Ab + (wr * 64 + mi * 16 + lr) * 32 + kq * 8);
#pragma unroll
    for (int ni = 0; ni < 4; ++ni)
      bfr[ni] = *(const s16x8*)(Bb + (wc * 64 + ni * 16 + lr) * 32 + kq * 8);
#pragma unroll
    for (int mi = 0; mi < 4; ++mi)
#pragma unroll
      for (int ni = 0; ni < 4; ++ni)
        acc[mi][ni] = __builtin_amdgcn_mfma_f32_16x16x32_bf16(
            af[mi], bfr[ni], acc[mi][ni], 0, 0, 0);
    __syncthreads();  // drains prefetch vmcnt + guards buffer swap
    cur = nxt;
  }

#pragma unroll
  for (int mi = 0; mi < 4; ++mi) {
    const int rbase = m0 + wr * 64 + mi * 16 + kq * 4;
    float b4[4];
#pragma unroll
    for (int j = 0; j < 4; ++j) b4[j] = b1[rbase + j];
#pragma unroll
    for (int ni = 0; ni < 4; ++ni) {
      const int col = n0 + wc * 64 + ni * 16 + lr;
      const float v0 = fmaxf(acc[mi][ni][0] + b4[0], 0.f);
      const float v1 = fmaxf(acc[mi][ni][1] + b4[1], 0.f);
      const float v2 = fmaxf(acc[mi][ni][2] + b4[2], 0.f);
      const float v3 = fmaxf(acc[mi][ni][3] + b4[3], 0.f);
      uint2 o;
      o.x = pack_bf16x2(v0, v1);
      o.y = pack_bf16x2(v2, v3);
      *(uint2*)(HT + (size_t)col * 1024 + rbase) = o;
    }
  }
}

// ---- layer-2 MFMA GEMM, 2-phase dbuf: rows<128 -> Fb bf16; 128..191 -> Sb f32
__global__ __launch_bounds__(256) void gemm2_mfma(
    const ushort* __restrict__ A2, const ushort* __restrict__ HT,
    const float* __restrict__ b2, float* __restrict__ C2,
    ushort* __restrict__ Fb) {
  constexpr int K = 1024;
  __shared__ ushort As[2 * 128 * 32];
  __shared__ ushort Bs[2 * 128 * 32];
  const int tid = threadIdx.x;
  const int l = tid & 63, w = tid >> 6;
  const int bid = blockIdx.x;
  const int newid = (bid & 7) * 32 + (bid >> 3);
  const int m0 = (newid & 1) * 128, n0 = (newid >> 1) * 128;
  const int wr = w >> 1, wc = w & 1;
  const int lr = l & 15, kq = l >> 4;

  f32x4 acc[4][4];
#pragma unroll
  for (int mi = 0; mi < 4; ++mi)
#pragma unroll
    for (int ni = 0; ni < 4; ++ni) acc[mi][ni] = (f32x4){0.f, 0.f, 0.f, 0.f};

  const int rA0 = tid >> 2;
  const int q8 = (tid & 3) * 8;
  ushort* AsW0 = As + (w * 64) * 8;
  ushort* AsW1 = As + (256 + w * 64) * 8;
  ushort* BsW0 = Bs + (w * 64) * 8;
  ushort* BsW1 = Bs + (256 + w * 64) * 8;
  const ushort* Arow0 = A2 + (size_t)(m0 + rA0) * K + q8;
  const ushort* Arow1 = A2 + (size_t)(m0 + rA0 + 64) * K + q8;
  const ushort* Brow0 = HT + (size_t)(n0 + rA0) * K + q8;
  const ushort* Brow1 = HT + (size_t)(n0 + rA0 + 64) * K + q8;

  gload_lds16(Arow0, AsW0);
  gload_lds16(Arow1, AsW1);
  gload_lds16(Brow0, BsW0);
  gload_lds16(Brow1, BsW1);
  __syncthreads();

  int cur = 0;
  for (int k0 = 0; k0 < K; k0 += 32) {
    const int nxt = cur ^ 1;
    if (k0 + 32 < K) {
      gload_lds16(Arow0 + k0 + 32, AsW0 + nxt * 4096);
      gload_lds16(Arow1 + k0 + 32, AsW1 + nxt * 4096);
      gload_lds16(Brow0 + k0 + 32, BsW0 + nxt * 4096);
      gload_lds16(Brow1 + k0 + 32, BsW1 + nxt * 4096);
    }
    const ushort* Ab = As + cur * 4096;
    const ushort* Bb = Bs + cur * 4096;
    s16x8 af[4], bfr[4];
#pragma unroll
    for (int mi = 0; mi < 4; ++mi)
      af[mi] = *(const s16x8*)(Ab + (wr * 64 + mi * 16 + lr) * 32 + kq * 8);
#pragma unroll
    for (int ni = 0; ni < 4; ++ni)
      bfr[ni] = *(const s16x8*)(Bb + (wc * 64 + ni * 16 + lr) * 32 + kq * 8);
#pragma unroll
    for (int mi = 0; mi < 4; ++mi)
#pragma unroll
      for (int ni = 0; ni < 4; ++ni)
        acc[mi][ni] = __builtin_amdgcn_mfma_f32_16x16x32_bf16(
            af[mi], bfr[ni], acc[mi][ni], 0, 0, 0);
    __syncthreads();
    cur = nxt;
  }

#pragma unroll
  for (int mi = 0; mi < 4; ++mi) {
    const int rbase = m0 + wr * 64 + mi * 16 + kq * 4;
    if (rbase < 192) {
      float b4[4];
#pragma unroll
      for (int j = 0; j < 4; ++j) b4[j] = b2[rbase + j];
      if (rbase < 128) {  // cluster features F -> bf16 [l][BNT]
#pragma unroll
        for (int ni = 0; ni < 4; ++ni) {
          const int col = n0 + wc * 64 + ni * 16 + lr;
#pragma unroll
          for (int j = 0; j < 4; ++j)
            Fb[(size_t)(rbase + j) * BNT + col] =
                f32_to_bf16_rne(acc[mi][ni][j] + b4[j]);
        }
      } else {  // scores -> f32
#pragma unroll
        for (int ni = 0; ni < 4; ++ni) {
          const int col = n0 + wc * 64 + ni * 16 + lr;
          float* cr = C2 + (size_t)rbase * BNT + col;
#pragma unroll
          for (int j = 0; j < 4; ++j)
            cr[(size_t)j * BNT] = acc[mi][ni][j] + b4[j];
        }
      }
    }
  }
}

// ---------------- Sinkhorn (log domain, 3 iters) -> P bf16 [b][m][n] --------
__global__ __launch_bounds__(256) void sinkhorn_b16(
    const float* __restrict__ S, const float* __restrict__ dustp,
    ushort* __restrict__ Pb) {
  const int b = blockIdx.x, tid = threadIdx.x;
  const int lane = tid & 63, wave = tid >> 6;
  __shared__ float Ms[65][256];
  __shared__ float u[65];
  __shared__ float v[256];
  const float dust = dustp[0];
  for (int idx = tid; idx < 16384; idx += 256) {
    const int m = idx >> 8, n = idx & 255;
    Ms[m][n] = S[m * BNT + b * 256 + n];
  }
  Ms[64][tid] = dust;
  v[tid] = 0.f;
  if (tid < 65) u[tid] = 0.f;
  const float norm = -logf(320.f);
  const float la_dust = norm + logf(192.f);
  __syncthreads();
  for (int it = 0; it < 3; ++it) {
    for (int i = wave; i < 65; i += 4) {
      const float x0 = Ms[i][lane] + v[lane];
      const float x1 = Ms[i][lane + 64] + v[lane + 64];
      const float x2 = Ms[i][lane + 128] + v[lane + 128];
      const float x3 = Ms[i][lane + 192] + v[lane + 192];
      float mm = fmaxf(fmaxf(x0, x1), fmaxf(x2, x3));
#pragma unroll
      for (int off = 32; off; off >>= 1) mm = fmaxf(mm, __shfl_xor(mm, off));
      float s = expf(x0 - mm) + expf(x1 - mm) + expf(x2 - mm) + expf(x3 - mm);
#pragma unroll
      for (int off = 32; off; off >>= 1) s += __shfl_xor(s, off);
      if (lane == 0) u[i] = (i == 64 ? la_dust : norm) - (logf(s) + mm);
    }
    __syncthreads();
    {
      const int n = tid;
      float mm = -1e30f;
      for (int i = 0; i < 65; ++i) mm = fmaxf(mm, Ms[i][n] + u[i]);
      float s = 0.f;
      for (int i = 0; i < 65; ++i) s += expf(Ms[i][n] + u[i] - mm);
      v[n] = norm - (logf(s) + mm);
    }
    __syncthreads();
  }
  for (int idx = tid; idx < 16384; idx += 256) {
    const int m = idx >> 8, n = idx & 255;
    Pb[b * 16384 + idx] =
        f32_to_bf16_rne(expf(Ms[m][n] + u[m] + v[n] - norm));
  }
}

// ---- VLAD via MFMA, direct from global (L2-resident bf16 F and P) ----------
// VL[b][l][m] = sum_n F[l][b*256+n] * P[b][m][n]; one block per batch.
__global__ __launch_bounds__(256) void vlad_mfma(const ushort* __restrict__ Fb,
                                                 const ushort* __restrict__ Pb,
                                                 float* __restrict__ VL) {
  const int b = blockIdx.x;
  const int tid = threadIdx.x, l = tid & 63, w = tid >> 6;
  const int lr = l & 15, ko = l >> 4;
  f32x4 acc[2][4];
#pragma unroll
  for (int li = 0; li < 2; ++li)
#pragma unroll
    for (int ni = 0; ni < 4; ++ni) acc[li][ni] = (f32x4){0.f, 0.f, 0.f, 0.f};
  const ushort* Fbase = Fb + b * 256;
  const ushort* Pbase = Pb + b * 16384;
#pragma unroll
  for (int ks = 0; ks < 8; ++ks) {
    const int k = ks * 32 + ko * 8;
    s16x8 bfr[4];
#pragma unroll
    for (int ni = 0; ni < 4; ++ni)
      bfr[ni] = *(const s16x8*)(Pbase + (ni * 16 + lr) * 256 + k);
#pragma unroll
    for (int li = 0; li < 2; ++li) {
      const s16x8 af =
          *(const s16x8*)(Fbase + (size_t)(w * 32 + li * 16 + lr) * BNT + k);
#pragma unroll
      for (int ni = 0; ni < 4; ++ni)
        acc[li][ni] = __builtin_amdgcn_mfma_f32_16x16x32_bf16(
            af, bfr[ni], acc[li][ni], 0, 0, 0);
    }
  }
#pragma unroll
  for (int li = 0; li < 2; ++li)
#pragma unroll
    for (int ni = 0; ni < 4; ++ni)
#pragma unroll
      for (int j = 0; j < 4; ++j) {
        const int ll = w * 32 + li * 16 + ko * 4 + j;
        const int m = ni * 16 + lr;
        VL[b * 8192 + ll * 64 + m] = acc[li][ni][j];
      }
}

// ---------------- finalize ---------------------------------------------------
__global__ __launch_bounds__(256) void finalize_kernel(
    const float* __restrict__ TK, const float* __restrict__ VL,
    float* __restrict__ out) {
  const int b = blockIdx.x, tid = threadIdx.x;
  const int lane = tid & 63, wave = tid >> 6;
  __shared__ float sred[4];
  __shared__ float ssm_part[4][64];
  __shared__ float invm_s[64];
  __shared__ float totals[1];
  const float* vl = &VL[b * 8192];
  float accv = 0.f;
  for (int k = 0; k < 32; ++k) {
    const float xv = vl[tid + 256 * k];
    accv = fmaf(xv, xv, accv);
  }
  ssm_part[wave][lane] = accv;
  const float tv = TK[b * 256 + tid];
  float ss = tv * tv;
#pragma unroll
  for (int off = 32; off; off >>= 1) ss += __shfl_down(ss, off);
  if (lane == 0) sred[wave] = ss;
  __syncthreads();
  const float sstok = sred[0] + sred[1] + sred[2] + sred[3];
  const float invtok = 1.f / fmaxf(sqrtf(sstok), 1e-12f);
  float tpart = 0.f;
  if (wave == 0) {
    const float s4 = ssm_part[0][tid] + ssm_part[1][tid] + ssm_part[2][tid] +
                     ssm_part[3][tid];
    const float inv = 1.f / fmaxf(sqrtf(s4), 1e-12f);
    invm_s[tid] = inv;
    tpart = s4 * inv * inv;
#pragma unroll
    for (int off = 32; off; off >>= 1) tpart += __shfl_down(tpart, off);
    if (lane == 0) totals[0] = tpart;
  }
  __syncthreads();
  const float total = totals[0] + sstok * invtok * invtok;
  const float invT = 1.f / fmaxf(sqrtf(total), 1e-12f);
  float* ob = &out[b * 8448];
  ob[tid] = tv * invtok * invT;
  for (int k = 0; k < 32; ++k) {
    const int idx = tid + 256 * k;
    ob[256 + idx] = vl[idx] * invm_s[idx & 63] * invT;
  }
}

// ================= fp32 fallback path kernels (unchanged) ===================
template <bool RELU>
__global__ __launch_bounds__(256) void gemm_tt(
    const float* __restrict__ A, const float* __restrict__ Bw,
    const float* __restrict__ bias, float* __restrict__ C, int K, int Nn) {
  __shared__ float As[16][68];
  __shared__ float Bs[16][68];
  const int tid = threadIdx.x;
  const int tx = tid & 15, ty = tid >> 4;
  const int n0 = blockIdx.x * 64;
  const int lrow = tid >> 2, lkq = (tid & 3) << 2;
  float acc[4][4];
#pragma unroll
  for (int r = 0; r < 4; ++r)
#pragma unroll
    for (int c = 0; c < 4; ++c) acc[r][c] = 0.f;
  for (int k0 = 0; k0 < K; k0 += 16) {
    const float4 av = *(const float4*)&A[lrow * K + k0 + lkq];
    const float4 bv = *(const float4*)&Bw[(n0 + lrow) * K + k0 + lkq];
    As[lkq + 0][lrow] = av.x;
    As[lkq + 1][lrow] = av.y;
    As[lkq + 2][lrow] = av.z;
    As[lkq + 3][lrow] = av.w;
    Bs[lkq + 0][lrow] = bv.x;
    Bs[lkq + 1][lrow] = bv.y;
    Bs[lkq + 2][lrow] = bv.z;
    Bs[lkq + 3][lrow] = bv.w;
    __syncthreads();
#pragma unroll
    for (int kk = 0; kk < 16; ++kk) {
      const float4 a4 = *(const float4*)&As[kk][ty << 2];
      const float4 b4 = *(const float4*)&Bs[kk][tx << 2];
      acc[0][0] = fmaf(a4.x, b4.x, acc[0][0]);
      acc[0][1] = fmaf(a4.x, b4.y, acc[0][1]);
      acc[0][2] = fmaf(a4.x, b4.z, acc[0][2]);
      acc[0][3] = fmaf(a4.x, b4.w, acc[0][3]);
      acc[1][0] = fmaf(a4.y, b4.x, acc[1][0]);
      acc[1][1] = fmaf(a4.y, b4.y, acc[1][1]);
      acc[1][2] = fmaf(a4.y, b4.z, acc[1][2]);
      acc[1][3] = fmaf(a4.y, b4.w, acc[1][3]);
      acc[2][0] = fmaf(a4.z, b4.x, acc[2][0]);
      acc[2][1] = fmaf(a4.z, b4.y, acc[2][1]);
      acc[2][2] = fmaf(a4.z, b4.z, acc[2][2]);
      acc[2][3] = fmaf(a4.z, b4.w, acc[2][3]);
      acc[3][0] = fmaf(a4.w, b4.x, acc[3][0]);
      acc[3][1] = fmaf(a4.w, b4.y, acc[3][1]);
      acc[3][2] = fmaf(a4.w, b4.z, acc[3][2]);
      acc[3][3] = fmaf(a4.w, b4.w, acc[3][3]);
    }
    __syncthreads();
  }
#pragma unroll
  for (int r = 0; r < 4; ++r) {
    const int row = (ty << 2) + r;
    float4 o;
    o.x = acc[r][0] + bias[n0 + (tx << 2) + 0];
    o.y = acc[r][1] + bias[n0 + (tx << 2) + 1];
    o.z = acc[r][2] + bias[n0 + (tx << 2) + 2];
    o.w = acc[r][3] + bias[n0 + (tx << 2) + 3];
    if (RELU) {
      o.x = fmaxf(o.x, 0.f);
      o.y = fmaxf(o.y, 0.f);
      o.z = fmaxf(o.z, 0.f);
      o.w = fmaxf(o.w, 0.f);
    }
    *(float4*)&C[row * Nn + n0 + (tx << 2)] = o;
  }
}

template <bool XVIEW, bool RELU>
__global__ __launch_bounds__(256) void gemm_tile(
    const float* __restrict__ A, const float* __restrict__ Bsrc,
    const float* __restrict__ bias, float* __restrict__ Cout, int K) {
  __shared__ float As[16][68];
  __shared__ float Bsh[16][68];
  const int tid = threadIdx.x;
  const int tx = tid & 15, ty = tid >> 4;
  const int rowBase = blockIdx.y * 64;
  const int colBase = blockIdx.x * 64;
  const int bb = colBase >> 8, n0 = colBase & 255;
  const int boff = XVIEW ? (bb * 393216 + n0) : colBase;
  const int la_row = tid >> 2, la_kq = (tid & 3) << 2;
  const int lb_k = tid >> 4, lb_c = (tid & 15) << 2;
  float acc[4][4];
#pragma unroll
  for (int r = 0; r < 4; ++r)
#pragma unroll
    for (int c = 0; c < 4; ++c) acc[r][c] = 0.f;
  for (int k0 = 0; k0 < K; k0 += 16) {
    const float4 av = *(const float4*)&A[(rowBase + la_row) * K + k0 + la_kq];
    float4 bv;
    if (XVIEW)
      bv = *(const float4*)&Bsrc[boff + (k0 + lb_k) * 256 + lb_c];
    else
      bv = *(const float4*)&Bsrc[(k0 + lb_k) * BNT + boff + lb_c];
    As[la_kq + 0][la_row] = av.x;
    As[la_kq + 1][la_row] = av.y;
    As[la_kq + 2][la_row] = av.z;
    As[la_kq + 3][la_row] = av.w;
    *(float4*)&Bsh[lb_k][lb_c] = bv;
    __syncthreads();
#pragma unroll
    for (int kk = 0; kk < 16; ++kk) {
      const float4 a4 = *(const float4*)&As[kk][ty << 2];
      const float4 b4 = *(const float4*)&Bsh[kk][tx << 2];
      acc[0][0] = fmaf(a4.x, b4.x, acc[0][0]);
      acc[0][1] = fmaf(a4.x, b4.y, acc[0][1]);
      acc[0][2] = fmaf(a4.x, b4.z, acc[0][2]);
      acc[0][3] = fmaf(a4.x, b4.w, acc[0][3]);
      acc[1][0] = fmaf(a4.y, b4.x, acc[1][0]);
      acc[1][1] = fmaf(a4.y, b4.y, acc[1][1]);
      acc[1][2] = fmaf(a4.y, b4.z, acc[1][2]);
      acc[1][3] = fmaf(a4.y, b4.w, acc[1][3]);
      acc[2][0] = fmaf(a4.z, b4.x, acc[2][0]);
      acc[2][1] = fmaf(a4.z, b4.y, acc[2][1]);
      acc[2][2] = fmaf(a4.z, b4.z, acc[2][2]);
      acc[2][3] = fmaf(a4.z, b4.w, acc[2][3]);
      acc[3][0] = fmaf(a4.w, b4.x, acc[3][0]);
      acc[3][1] = fmaf(a4.w, b4.y, acc[3][1]);
      acc[3][2] = fmaf(a4.w, b4.z, acc[3][2]);
      acc[3][3] = fmaf(a4.w, b4.w, acc[3][3]);
    }
    __syncthreads();
  }
#pragma unroll
  for (int r = 0; r < 4; ++r) {
    const int row = rowBase + (ty << 2) + r;
    const float bsv = bias[row];
    float4 o;
    o.x = acc[r][0] + bsv;
    o.y = acc[r][1] + bsv;
    o.z = acc[r][2] + bsv;
    o.w = acc[r][3] + bsv;
    if (RELU) {
      o.x = fmaxf(o.x, 0.f);
      o.y = fmaxf(o.y, 0.f);
      o.z = fmaxf(o.z, 0.f);
      o.w = fmaxf(o.w, 0.f);
    }
    *(float4*)&Cout[row * BNT + colBase + (tx << 2)] = o;
  }
}

__global__ __launch_bounds__(256) void sinkhorn_kernel(
    const float* __restrict__ S, const float* __restrict__ dustp,
    float* __restrict__ P) {
  const int b = blockIdx.x, tid = threadIdx.x;
  const int lane = tid & 63, wave = tid >> 6;
  __shared__ float Ms[65][256];
  __shared__ float u[65];
  __shared__ float v[256];
  const float dust = dustp[0];
  for (int idx = tid; idx < 16384; idx += 256) {
    const int m = idx >> 8, n = idx & 255;
    Ms[m][n] = S[m * BNT + b * 256 + n];
  }
  Ms[64][tid] = dust;
  v[tid] = 0.f;
  if (tid < 65) u[tid] = 0.f;
  const float norm = -logf(320.f);
  const float la_dust = norm + logf(192.f);
  __syncthreads();
  for (int it = 0; it < 3; ++it) {
    for (int i = wave; i < 65; i += 4) {
      const float x0 = Ms[i][lane] + v[lane];
      const float x1 = Ms[i][lane + 64] + v[lane + 64];
      const float x2 = Ms[i][lane + 128] + v[lane + 128];
      const float x3 = Ms[i][lane + 192] + v[lane + 192];
      float mm = fmaxf(fmaxf(x0, x1), fmaxf(x2, x3));
#pragma unroll
      for (int off = 32; off; off >>= 1) mm = fmaxf(mm, __shfl_xor(mm, off));
      float s = expf(x0 - mm) + expf(x1 - mm) + expf(x2 - mm) + expf(x3 - mm);
#pragma unroll
      for (int off = 32; off; off >>= 1) s += __shfl_xor(s, off);
      if (lane == 0) u[i] = (i == 64 ? la_dust : norm) - (logf(s) + mm);
    }
    __syncthreads();
    {
      const int n = tid;
      float mm = -1e30f;
      for (int i = 0; i < 65; ++i) mm = fmaxf(mm, Ms[i][n] + u[i]);
      float s = 0.f;
      for (int i = 0; i < 65; ++i) s += expf(Ms[i][n] + u[i] - mm);
      v[n] = norm - (logf(s) + mm);
    }
    __syncthreads();
  }
  for (int idx = tid; idx < 16384; idx += 256) {
    const int m = idx >> 8, n = idx & 255;
    P[b * 16384 + idx] = expf(Ms[m][n] + u[m] + v[n] - norm);
  }
}

__device__ __forceinline__ int ps_idx(int m, int n) {
  return m * 256 + ((((n >> 2) ^ (m & 7)) << 2) | (n & 3));
}
__global__ __launch_bounds__(256) void vlad_kernel(const float* __restrict__ F,
                                                   const float* __restrict__ P,
                                                   float* __restrict__ VL) {
  const int b = blockIdx.x, half = blockIdx.y;
  const int tid = threadIdx.x;
  const int m = tid & 63, lg = tid >> 6;
  __shared__ float ps[64 * 256];
  for (int idx = tid; idx < 16384; idx += 256) {
    const int mm = idx >> 8, n = idx & 255;
    ps[ps_idx(mm, n)] = P[b * 16384 + idx];
  }
  __syncthreads();
  float acc[16];
#pragma unroll
  for (int i = 0; i < 16; ++i) acc[i] = 0.f;
  for (int i = 0; i < 16; ++i) {
    const int ll = half * 64 + lg + 4 * i;
    const float* frow = &F[(size_t)ll * BNT + b * 256];
    float a = 0.f;
#pragma unroll 8
    for (int nq = 0; nq < 64; ++nq) {
      const float4 f4 = *(const float4*)&frow[nq << 2];
      const float4 p4 = *(const float4*)&ps[m * 256 + ((nq ^ (m & 7)) << 2)];
      a = fmaf(f4.x, p4.x, a);
      a = fmaf(f4.y, p4.y, a);
      a = fmaf(f4.z, p4.z, a);
      a = fmaf(f4.w, p4.w, a);
    }
    acc[i] = a;
  }
#pragma unroll
  for (int i = 0; i < 16; ++i) {
    const int ll = half * 64 + lg + 4 * i;
    VL[b * 8192 + ll * 64 + m] = acc[i];
  }
}

extern "C" void kernel_launch(void* const* d_in, const int* in_sizes, int n_in,
                              void* d_out, int out_size, void* d_ws,
                              size_t ws_size, hipStream_t stream) {
  const float* x = (const float*)d_in[0];
  const float* t = (const float*)d_in[1];
  const float* Wt1 = (const float*)d_in[2];
  const float* bt1 = (const float*)d_in[3];
  const float* Wt2 = (const float*)d_in[4];
  const float* bt2 = (const float*)d_in[5];
  const float* Wc1 = (const float*)d_in[6];
  const float* bc1 = (const float*)d_in[7];
  const float* Wc2 = (const float*)d_in[8];
  const float* bc2 = (const float*)d_in[9];
  const float* Ws1 = (const float*)d_in[10];
  const float* bs1 = (const float*)d_in[11];
  const float* Ws2 = (const float*)d_in[12];
  const float* bs2 = (const float*)d_in[13];
  const float* dust = (const float*)d_in[14];
  float* out = (float*)d_out;

  if (ws_size >= 97714176ull) {
    // Byte layout (stream-ordered overlays):
    // [0, 50331648)        XT bf16 16384x1536 (dead after gemm1)
    //   pre-transpose overlay (token scratch): Tb@0, Wt1b@196608,
    //     Wt2b@1769472, Pt@2031616, Hb@2555904
    //   post-gemm1 overlay: Pb16@0 (2MB), VL@4194304 (2MB), Fb16@8388608 (4MB)
    // [50331648, 83886080) HT bf16 16384x1024 (dead after gemm2)
    // [83886080, 96468992) C2 f32 (only rows 128..191 = Sb written);
    //                      pre-gemm2 overlay: A1 stacked (Wc1b, Ws1b)
    // [96468992, 96993280) A2 bf16 256x1024
    // [96993280, 96994304) b2 f32 256
    // [96994304, 97059840) TK f32 64x256
    // [97059840, 97063936) b1 f32 1024
    char* base = (char*)d_ws;
    ushort* Tb = (ushort*)base;
    ushort* Wt1b = (ushort*)(base + 196608);
    ushort* Wt2b = (ushort*)(base + 1769472);
    float* Pt = (float*)(base + 2031616);
    ushort* Hb = (ushort*)(base + 2555904);
    ushort* XT = (ushort*)base;
    ushort* Pb = (ushort*)base;                 // bf16 P, post-gemm1
    float* VL = (float*)(base + 4194304);
    ushort* Fb = (ushort*)(base + 8388608);     // bf16 F, post-gemm1
    ushort* HT = (ushort*)(base + 50331648);
    float* C2 = (float*)(base + 83886080);
    ushort* A1 = (ushort*)(base + 83886080);
    ushort* Wc1b = A1;
    ushort* Ws1b = (ushort*)(base + 85458944);
    ushort* A2 = (ushort*)(base + 96468992);
    float* b2 = (float*)(base + 96993280);
    float* TK = (float*)(base + 96994304);
    float* b1 = (float*)(base + 97059840);
    float* Sb = C2 + (size_t)128 * BNT;         // f32 score rows

    prep_all<<<2788, 256, 0, stream>>>(t, Wt1, Wt2, Wc1, Ws1, bc1, bs1, Wc2,
                                       Ws2, bc2, bs2, Tb, Wt1b, Wt2b, Wc1b,
                                       Ws1b, b1, A2, b2);
    token1_mfma<<<dim3(8, 4), 256, 0, stream>>>(Tb, Wt1b, Pt);
    token1_reduce<<<64, 256, 0, stream>>>(Pt, bt1, Hb);
    token2_mfma<<<4, 256, 0, stream>>>(Hb, Wt2b, bt2, TK);
    transpose_x_bf16<<<dim3(24, 64), 256, 0, stream>>>(x, XT);
    gemm1_mfma<<<1024, 256, 0, stream>>>(A1, XT, b1, HT);
    gemm2_mfma<<<256, 256, 0, stream>>>(A2, HT, b2, C2, Fb);
    sinkhorn_b16<<<64, 256, 0, stream>>>(Sb, dust, Pb);
    vlad_mfma<<<64, 256, 0, stream>>>(Fb, Pb, VL);
    finalize_kernel<<<64, 256, 0, stream>>>(TK, VL, out);
  } else {
    // fp32 fallback (fits 52.6 MB)
    float* ws = (float*)d_ws;
    float* H = ws;
    float* F = H + 512 * BNT;
    float* Sb = F + 128 * BNT;
    float* P = Sb + 64 * BNT;
    float* VL = P + 64 * BNT;
    float* TK = VL + 64 * 8192;
    float* Hh = P;

    gemm_tt<true><<<dim3(8, 1), 256, 0, stream>>>(t, Wt1, bt1, Hh, 1536, 512);
    gemm_tt<false><<<dim3(4, 1), 256, 0, stream>>>(Hh, Wt2, bt2, TK, 512, 256);
    gemm_tile<true, true><<<dim3(256, 8), 256, 0, stream>>>(Wc1, x, bc1, H, 1536);
    gemm_tile<false, false><<<dim3(256, 2), 256, 0, stream>>>(Wc2, H, bc2, F, 512);
    gemm_tile<true, true><<<dim3(256, 8), 256, 0, stream>>>(Ws1, x, bs1, H, 1536);
    gemm_tile<false, false><<<dim3(256, 1), 256, 0, stream>>>(Ws2, H, bs2, Sb, 512);
    sinkhorn_kernel<<<64, 256, 0, stream>>>(Sb, dust, P);
    vlad_kernel<<<dim3(64, 2), 256, 0, stream>>>(F, P, VL);
    finalize_kernel<<<64, 256, 0, stream>>>(TK, VL, out);
  }
}